// Round 3
// baseline (684.171 us; speedup 1.0000x reference)
//
#include <hip/hip_runtime.h>
#include <math.h>

#define LATENT 256
#define HIDDEN 512
#define NODE_F 128
#define MAX_NODES 50
#define NPAIRS 1225        // 50*49/2
#define BATCH 128
#define NODE_OUT 6400      // MAX_NODES*NODE_F
#define MTILE 32           // edge rows per block

typedef __attribute__((ext_vector_type(8))) short short8;
typedef __attribute__((ext_vector_type(4))) float float4v;

__device__ __forceinline__ float bf2f(ushort u) {
    union { unsigned int i; float f; } v; v.i = ((unsigned int)u) << 16; return v.f;
}
__device__ __forceinline__ ushort f2bf(float f) {
    union { unsigned int i; float f; } v; v.f = f;
    unsigned int r = v.i + 0x7fffu + ((v.i >> 16) & 1u);   // RNE
    return (ushort)(r >> 16);
}
__device__ __forceinline__ float sigmoidf(float x) {
    return 1.0f / (1.0f + __expf(-x));
}

// ---------------- prep: fp32->bf16 converts + weight transposes into ws
// ew1T[n][k]=ew1[k][n] (bf16), ew2T[n][k]=ew2[k][n] (bf16), zb = bf16(z)
__global__ void k_prep(const float* __restrict__ ew1, const float* __restrict__ ew2,
                       const float* __restrict__ z,
                       ushort* __restrict__ ew1T, ushort* __restrict__ ew2T,
                       ushort* __restrict__ zb) {
    int t = blockIdx.x * blockDim.x + threadIdx.x;
    if (t < 512 * 512) {
        int n = t >> 9, k = t & 511;
        ew1T[t] = f2bf(ew1[k * 512 + n]);
    } else if (t < 512 * 512 + 256 * 512) {
        int u = t - 512 * 512;
        int n = u >> 9, k = u & 511;
        ew2T[u] = f2bf(ew2[k * 256 + n]);
    } else if (t < 512 * 512 + 256 * 512 + BATCH * LATENT) {
        int u = t - (512 * 512 + 256 * 512);
        zb[u] = f2bf(z[u]);
    }
}

// ---------------- node MLP layer 1: h1 = relu(z @ nw1 + nb1)  (fp32 in/out)
__global__ void k_node_h1(const float* __restrict__ z, const float* __restrict__ nw1,
                          const float* __restrict__ nb1, float* __restrict__ h1) {
    __shared__ float zs[LATENT];
    int r = blockIdx.x;
    int o = threadIdx.x;                 // 512 threads
    if (o < LATENT) zs[o] = z[r * LATENT + o];
    __syncthreads();
    float acc = 0.f;
#pragma unroll 8
    for (int k = 0; k < LATENT; k++) acc += zs[k] * nw1[k * HIDDEN + o];
    acc += nb1[o];
    h1[r * HIDDEN + o] = fmaxf(acc, 0.f);
}

// ---------------- node MLP layer 2: h2 = relu(h1 @ nw2 + nb2)
__global__ void k_node_h2(const float* __restrict__ h1, const float* __restrict__ nw2,
                          const float* __restrict__ nb2, float* __restrict__ h2) {
    __shared__ float hs[HIDDEN];
    int r = blockIdx.x;
    int o = threadIdx.x;                 // 512 threads
    hs[o] = h1[r * HIDDEN + o];
    __syncthreads();
    float acc = 0.f;
#pragma unroll 8
    for (int k = 0; k < HIDDEN; k++) acc += hs[k] * nw2[k * HIDDEN + o];
    acc += nb2[o];
    h2[r * HIDDEN + o] = fmaxf(acc, 0.f);
}

// ---------------- node MLP layer 3: logits -> node_probs (fp32 out) + node_feats (bf16, ws)
__global__ void k_node_out(const float* __restrict__ h2, const float* __restrict__ nw3,
                           const float* __restrict__ nb3, float* __restrict__ node_probs,
                           ushort* __restrict__ node_feats) {
    __shared__ float hs[HIDDEN];
    int r = blockIdx.x / 25;
    int c = blockIdx.x % 25;
    int tid = threadIdx.x;               // 256 threads
    hs[tid] = h2[r * HIDDEN + tid];
    hs[tid + 256] = h2[r * HIDDEN + tid + 256];
    __syncthreads();
    int o = c * 256 + tid;
    float acc = 0.f;
#pragma unroll 8
    for (int k = 0; k < HIDDEN; k++) acc += hs[k] * nw3[k * NODE_OUT + o];
    acc += nb3[o];
    node_feats[r * NODE_OUT + o] = f2bf(acc);
    node_probs[r * NODE_OUT + o] = sigmoidf(acc);
}

// ---------------- fused edge MLP: per 32-row tile, gather->GEMM1->relu->GEMM2->relu->dot->sigmoid
__global__ __launch_bounds__(256) void k_edge(
    const ushort* __restrict__ zb, const ushort* __restrict__ nf,
    const ushort* __restrict__ ew1T, const ushort* __restrict__ ew2T,
    const float* __restrict__ ew3, const float* __restrict__ eb1,
    const float* __restrict__ eb2, const float* __restrict__ eb3,
    float* __restrict__ out_edges)
{
    __shared__ __align__(16) ushort h1[MTILE][HIDDEN + 8];   // 33,280 B
    __shared__ __align__(16) ushort h2[MTILE][256 + 8];      // 16,896 B
    __shared__ int zo[MTILE], io_[MTILE], jo[MTILE];

    int tid = threadIdx.x;
    if (tid < MTILE) {
        int r = blockIdx.x * MTILE + tid;
        int b = r / NPAIRS;
        int p = r - b * NPAIRS;
        int i = 0, off = 0;
        while (p - off >= MAX_NODES - 1 - i) { off += MAX_NODES - 1 - i; ++i; }
        int j = i + 1 + (p - off);
        zo[tid]  = b * LATENT;
        io_[tid] = (b * MAX_NODES + i) * NODE_F;
        jo[tid]  = (b * MAX_NODES + j) * NODE_F;
    }
    __syncthreads();

    int wave = tid >> 6;       // 0..3
    int lane = tid & 63;
    int m16  = lane & 15;      // A row / C col index
    int quad = lane >> 4;      // 0..3

    // per-lane gather base pointers for the two 16-row A sub-tiles;
    // segment k-ranges: [0,256)->z, [256,384)->node_i, [384,512)->node_j
    const ushort* pA[2][3];
#pragma unroll
    for (int mt = 0; mt < 2; mt++) {
        int lr = mt * 16 + m16;
        pA[mt][0] = zb + zo[lr];
        pA[mt][1] = nf + io_[lr] - LATENT;
        pA[mt][2] = nf + jo[lr]  - (LATENT + NODE_F);
    }

    // ---- GEMM1: (32 x 512) x (512 x 512); wave covers cols [wave*128, wave*128+128)
    float4v acc1[2][8];
#pragma unroll
    for (int mt = 0; mt < 2; mt++)
#pragma unroll
        for (int nt = 0; nt < 8; nt++) acc1[mt][nt] = (float4v)(0.f);

    for (int k0 = 0; k0 < HIDDEN; k0 += 32) {
        int kk = k0 + quad * 8;                       // this lane's 8-wide k chunk
        int seg = (kk >= LATENT) + (kk >= LATENT + NODE_F);
        short8 a0 = *(const short8*)(pA[0][seg] + kk);
        short8 a1 = *(const short8*)(pA[1][seg] + kk);
#pragma unroll
        for (int nt = 0; nt < 8; nt++) {
            int n = wave * 128 + nt * 16 + m16;
            short8 bf = *(const short8*)(ew1T + n * HIDDEN + kk);
            acc1[0][nt] = __builtin_amdgcn_mfma_f32_16x16x32_bf16(a0, bf, acc1[0][nt], 0, 0, 0);
            acc1[1][nt] = __builtin_amdgcn_mfma_f32_16x16x32_bf16(a1, bf, acc1[1][nt], 0, 0, 0);
        }
    }
    // epilogue 1: bias + relu -> bf16 -> LDS h1. C layout: col=lane&15, row=quad*4+t
#pragma unroll
    for (int nt = 0; nt < 8; nt++) {
        int col = wave * 128 + nt * 16 + m16;
        float bias = eb1[col];
#pragma unroll
        for (int mt = 0; mt < 2; mt++)
#pragma unroll
            for (int t = 0; t < 4; t++) {
                int row = mt * 16 + quad * 4 + t;
                h1[row][col] = f2bf(fmaxf(acc1[mt][nt][t] + bias, 0.f));
            }
    }
    __syncthreads();

    // ---- GEMM2: (32 x 512) x (512 x 256); wave covers cols [wave*64, wave*64+64)
    float4v acc2[2][4];
#pragma unroll
    for (int mt = 0; mt < 2; mt++)
#pragma unroll
        for (int nt = 0; nt < 4; nt++) acc2[mt][nt] = (float4v)(0.f);

    for (int k0 = 0; k0 < HIDDEN; k0 += 32) {
        int kk = k0 + quad * 8;
        short8 a0 = *(const short8*)&h1[m16][kk];
        short8 a1 = *(const short8*)&h1[16 + m16][kk];
#pragma unroll
        for (int nt = 0; nt < 4; nt++) {
            int n = wave * 64 + nt * 16 + m16;
            short8 bf = *(const short8*)(ew2T + n * HIDDEN + kk);
            acc2[0][nt] = __builtin_amdgcn_mfma_f32_16x16x32_bf16(a0, bf, acc2[0][nt], 0, 0, 0);
            acc2[1][nt] = __builtin_amdgcn_mfma_f32_16x16x32_bf16(a1, bf, acc2[1][nt], 0, 0, 0);
        }
    }
#pragma unroll
    for (int nt = 0; nt < 4; nt++) {
        int col = wave * 64 + nt * 16 + m16;
        float bias = eb2[col];
#pragma unroll
        for (int mt = 0; mt < 2; mt++)
#pragma unroll
            for (int t = 0; t < 4; t++) {
                int row = mt * 16 + quad * 4 + t;
                h2[row][col] = f2bf(fmaxf(acc2[mt][nt][t] + bias, 0.f));
            }
    }
    __syncthreads();

    // ---- GEMM3: per-row 256-dot with ew3 + bias -> sigmoid. 8 lanes per row.
    int row = tid >> 3;       // 0..31
    int t8  = tid & 7;
    float s = 0.f;
#pragma unroll 8
    for (int k = t8 * 32; k < t8 * 32 + 32; k++)
        s += bf2f(h2[row][k]) * ew3[k];
    s += __shfl_xor(s, 1);
    s += __shfl_xor(s, 2);
    s += __shfl_xor(s, 4);
    if (t8 == 0) {
        float v = s + eb3[0];
        out_edges[blockIdx.x * MTILE + row] = sigmoidf(v);
    }
}

extern "C" void kernel_launch(void* const* d_in, const int* in_sizes, int n_in,
                              void* d_out, int out_size, void* d_ws, size_t ws_size,
                              hipStream_t stream) {
    const float* z   = (const float*)d_in[0];
    const float* nw1 = (const float*)d_in[1];
    const float* nb1 = (const float*)d_in[2];
    const float* nw2 = (const float*)d_in[3];
    const float* nb2 = (const float*)d_in[4];
    const float* nw3 = (const float*)d_in[5];
    const float* nb3 = (const float*)d_in[6];
    const float* ew1 = (const float*)d_in[7];
    const float* eb1 = (const float*)d_in[8];
    const float* ew2 = (const float*)d_in[9];
    const float* eb2 = (const float*)d_in[10];
    const float* ew3 = (const float*)d_in[11];
    const float* eb3 = (const float*)d_in[12];

    char* ws = (char*)d_ws;
    float*  h1    = (float*)(ws);                    // 128*512*4 = 262144 B
    float*  h2    = (float*)(ws + 262144);           // 262144 B
    ushort* nf    = (ushort*)(ws + 524288);          // 128*6400*2 = 1638400 B
    ushort* ew1T  = (ushort*)(ws + 2162688);         // 512*512*2 = 524288 B
    ushort* ew2T  = (ushort*)(ws + 2686976);         // 256*512*2 = 262144 B
    ushort* zb    = (ushort*)(ws + 2949120);         // 128*256*2 = 65536 B
                                                     // total 3014656 B

    float* out_nodes = (float*)d_out;                // 128*50*128 = 819200 elems
    float* out_edges = out_nodes + BATCH * NODE_OUT; // 128*1225 = 156800 elems

    // prep threads: 262144 + 131072 + 32768 = 425984 = 1664 * 256
    k_prep<<<1664, 256, 0, stream>>>(ew1, ew2, z, ew1T, ew2T, zb);
    k_node_h1<<<BATCH, 512, 0, stream>>>(z, nw1, nb1, h1);
    k_node_h2<<<BATCH, 512, 0, stream>>>(h1, nw2, nb2, h2);
    k_node_out<<<BATCH * 25, 256, 0, stream>>>(h2, nw3, nb3, out_nodes, nf);
    k_edge<<<(BATCH * NPAIRS) / MTILE, 256, 0, stream>>>(zb, nf, ew1T, ew2T, ew3,
                                                         eb1, eb2, eb3, out_edges);
}

// Round 4
// 390.618 us; speedup vs baseline: 1.7515x; 1.7515x over previous
//
#include <hip/hip_runtime.h>
#include <math.h>

#define LATENT 256
#define HIDDEN 512
#define NODE_F 128
#define MAX_NODES 50
#define NPAIRS 1225        // 50*49/2
#define BATCH 128
#define NODE_OUT 6400      // MAX_NODES*NODE_F
#define MTILE 32           // edge rows per block
#define NNODES 6400        // BATCH*MAX_NODES

typedef __attribute__((ext_vector_type(8))) short short8;
typedef __attribute__((ext_vector_type(4))) float float4v;

__device__ __forceinline__ float bf2f(ushort u) {
    union { unsigned int i; float f; } v; v.i = ((unsigned int)u) << 16; return v.f;
}
__device__ __forceinline__ ushort f2bf(float f) {
    union { unsigned int i; float f; } v; v.f = f;
    unsigned int r = v.i + 0x7fffu + ((v.i >> 16) & 1u);   // RNE
    return (ushort)(r >> 16);
}
__device__ __forceinline__ float sigmoidf(float x) {
    return 1.0f / (1.0f + __expf(-x));
}

// ---------------- small weight transposes (bf16):
// ew2T[n][k] = ew2[k][n]  (256x512)
// wijT[n][k] = n<512 ? ew1[256+k][n] : ew1[384+k][n-512]   (1024x128)  [W_i|W_j]^T
__global__ void k_prep(const float* __restrict__ ew1, const float* __restrict__ ew2,
                       ushort* __restrict__ ew2T, ushort* __restrict__ wijT) {
    int t = blockIdx.x * blockDim.x + threadIdx.x;
    if (t < 256 * 512) {
        int n = t >> 9, k = t & 511;
        ew2T[t] = f2bf(ew2[k * 256 + n]);
    } else if (t < 256 * 512 + 1024 * 128) {
        int u = t - 256 * 512;
        int n = u >> 7, k = u & 127;
        float s = (n < 512) ? ew1[(256 + k) * 512 + n] : ew1[(384 + k) * 512 + (n - 512)];
        wijT[u] = f2bf(s);
    }
}

// ---------------- nw3T[n][k] = bf16(nw3[k][n]), LDS-tiled (64x64 tiles)
__global__ void k_tr3(const float* __restrict__ nw3, ushort* __restrict__ nw3T) {
    __shared__ float tile[64][65];
    int k0 = (blockIdx.x & 7) * 64;     // 8 k-tiles
    int n0 = (blockIdx.x >> 3) * 64;    // 100 n-tiles
    int tx = threadIdx.x & 63, ty = threadIdx.x >> 6;  // 64 x 4
#pragma unroll
    for (int r = 0; r < 16; r++) {
        int row = r * 4 + ty;
        tile[row][tx] = nw3[(k0 + row) * NODE_OUT + n0 + tx];
    }
    __syncthreads();
#pragma unroll
    for (int c = 0; c < 16; c++) {
        int n = c * 4 + ty;
        nw3T[(size_t)(n0 + n) * HIDDEN + k0 + tx] = f2bf(tile[tx][n]);
    }
}

// ---------------- Zc = z @ W_z + eb1   (128x512 fp32; W_z = ew1[0:256,:]; no relu)
__global__ void k_zc(const float* __restrict__ z, const float* __restrict__ ew1,
                     const float* __restrict__ eb1, float* __restrict__ Zc) {
    __shared__ float zs[LATENT];
    int r = blockIdx.x;
    int o = threadIdx.x;                 // 512 threads
    if (o < LATENT) zs[o] = z[r * LATENT + o];
    __syncthreads();
    float acc = 0.f;
#pragma unroll 8
    for (int k = 0; k < LATENT; k++) acc += zs[k] * ew1[k * HIDDEN + o];
    Zc[r * HIDDEN + o] = acc + eb1[o];
}

// ---------------- node MLP layer 1: h1 = relu(z @ nw1 + nb1)  (fp32 out)
__global__ void k_node_h1(const float* __restrict__ z, const float* __restrict__ nw1,
                          const float* __restrict__ nb1, float* __restrict__ h1) {
    __shared__ float zs[LATENT];
    int r = blockIdx.x;
    int o = threadIdx.x;                 // 512 threads
    if (o < LATENT) zs[o] = z[r * LATENT + o];
    __syncthreads();
    float acc = 0.f;
#pragma unroll 8
    for (int k = 0; k < LATENT; k++) acc += zs[k] * nw1[k * HIDDEN + o];
    acc += nb1[o];
    h1[r * HIDDEN + o] = fmaxf(acc, 0.f);
}

// ---------------- node MLP layer 2: h2b = bf16(relu(h1 @ nw2 + nb2))
__global__ void k_node_h2(const float* __restrict__ h1, const float* __restrict__ nw2,
                          const float* __restrict__ nb2, ushort* __restrict__ h2b) {
    __shared__ float hs[HIDDEN];
    int r = blockIdx.x;
    int o = threadIdx.x;                 // 512 threads
    hs[o] = h1[r * HIDDEN + o];
    __syncthreads();
    float acc = 0.f;
#pragma unroll 8
    for (int k = 0; k < HIDDEN; k++) acc += hs[k] * nw2[k * HIDDEN + o];
    acc += nb2[o];
    h2b[r * HIDDEN + o] = f2bf(fmaxf(acc, 0.f));
}

// ---------------- node layer 3 via MFMA: logits = h2b @ nw3T^T + nb3
// grid = 100 (N-tiles of 64); wave w covers cols [n0+w*16, +16); all 128 rows.
__global__ __launch_bounds__(256) void k_node_out_mfma(
    const ushort* __restrict__ h2b, const ushort* __restrict__ nw3T,
    const float* __restrict__ nb3, float* __restrict__ node_probs,
    ushort* __restrict__ node_feats)
{
    int tid = threadIdx.x;
    int wave = tid >> 6, lane = tid & 63;
    int m16 = lane & 15, quad = lane >> 4;
    int n0 = blockIdx.x * 64;
    int col = n0 + wave * 16 + m16;

    float4v acc[8];
#pragma unroll
    for (int mt = 0; mt < 8; mt++) acc[mt] = (float4v)(0.f);

    const ushort* bb = nw3T + (size_t)col * HIDDEN;
    for (int k0 = 0; k0 < HIDDEN; k0 += 32) {
        int kk = k0 + quad * 8;
        short8 b = *(const short8*)(bb + kk);
#pragma unroll
        for (int mt = 0; mt < 8; mt++) {
            short8 a = *(const short8*)(h2b + (mt * 16 + m16) * HIDDEN + kk);
            acc[mt] = __builtin_amdgcn_mfma_f32_16x16x32_bf16(a, b, acc[mt], 0, 0, 0);
        }
    }
    float bias = nb3[col];
#pragma unroll
    for (int mt = 0; mt < 8; mt++)
#pragma unroll
        for (int t = 0; t < 4; t++) {
            int row = mt * 16 + quad * 4 + t;
            float v = acc[mt][t] + bias;
            node_probs[(size_t)row * NODE_OUT + col] = sigmoidf(v);
            node_feats[(size_t)row * NODE_OUT + col] = f2bf(v);
        }
}

// ---------------- UV = node_feats @ [W_i|W_j]   (6400 x 1024, bf16 out)
// grid = 200 m-tiles x 2 n-halves; wave covers 128 cols (nt=8), 32 rows (mt=2)
__global__ __launch_bounds__(256) void k_uv(
    const ushort* __restrict__ nf, const ushort* __restrict__ wijT,
    ushort* __restrict__ UV)
{
    int tid = threadIdx.x;
    int wave = tid >> 6, lane = tid & 63;
    int m16 = lane & 15, quad = lane >> 4;
    int bm = blockIdx.x >> 1, bn = blockIdx.x & 1;
    int base = bn * 512 + wave * 128;

    float4v acc[2][8];
#pragma unroll
    for (int mt = 0; mt < 2; mt++)
#pragma unroll
        for (int nt = 0; nt < 8; nt++) acc[mt][nt] = (float4v)(0.f);

    for (int k0 = 0; k0 < NODE_F; k0 += 32) {
        int kk = k0 + quad * 8;
        short8 a0 = *(const short8*)(nf + (bm * 32 + m16) * NODE_F + kk);
        short8 a1 = *(const short8*)(nf + (bm * 32 + 16 + m16) * NODE_F + kk);
#pragma unroll
        for (int nt = 0; nt < 8; nt++) {
            int n = base + nt * 16 + m16;
            short8 b = *(const short8*)(wijT + n * NODE_F + kk);
            acc[0][nt] = __builtin_amdgcn_mfma_f32_16x16x32_bf16(a0, b, acc[0][nt], 0, 0, 0);
            acc[1][nt] = __builtin_amdgcn_mfma_f32_16x16x32_bf16(a1, b, acc[1][nt], 0, 0, 0);
        }
    }
#pragma unroll
    for (int nt = 0; nt < 8; nt++) {
        int colg = base + nt * 16 + m16;
#pragma unroll
        for (int mt = 0; mt < 2; mt++)
#pragma unroll
            for (int t = 0; t < 4; t++) {
                int rr = bm * 32 + mt * 16 + quad * 4 + t;
                UV[(size_t)rr * 1024 + colg] = f2bf(acc[mt][nt][t]);
            }
    }
}

// ---------------- fused edge: assemble h1 = relu(Zc[b]+U[i]+V[j]) -> GEMM2 -> dot -> sigmoid
__global__ __launch_bounds__(256) void k_edge2(
    const float* __restrict__ Zc, const ushort* __restrict__ UV,
    const ushort* __restrict__ ew2T, const float* __restrict__ ew3,
    const float* __restrict__ eb2, const float* __restrict__ eb3,
    float* __restrict__ out_edges)
{
    __shared__ __align__(16) ushort h1[MTILE][HIDDEN + 8];   // 33,280 B
    __shared__ float part[MTILE][4];
    __shared__ int zo[MTILE], uo[MTILE], vo[MTILE];

    int tid = threadIdx.x;
    if (tid < MTILE) {
        int r = blockIdx.x * MTILE + tid;
        int b = r / NPAIRS;
        int p = r - b * NPAIRS;
        int i = 0, off = 0;
        while (p - off >= MAX_NODES - 1 - i) { off += MAX_NODES - 1 - i; ++i; }
        int j = i + 1 + (p - off);
        zo[tid] = b * HIDDEN;
        uo[tid] = (b * MAX_NODES + i) * 1024;
        vo[tid] = (b * MAX_NODES + j) * 1024 + 512;
    }
    __syncthreads();

    // ---- assemble h1 tile: 32 rows x 512 cols, each thread: 1 row x 64 cols
    {
        int r = tid >> 3, cg = (tid & 7) * 64;
        const float*  zp = Zc + zo[r] + cg;
        const ushort* up = UV + uo[r] + cg;
        const ushort* vp = UV + vo[r] + cg;
#pragma unroll
        for (int g = 0; g < 64; g += 8) {
            short8 u8 = *(const short8*)(up + g);
            short8 v8 = *(const short8*)(vp + g);
            float4v z0 = *(const float4v*)(zp + g);
            float4v z1 = *(const float4v*)(zp + g + 4);
            short8 hh;
#pragma unroll
            for (int e = 0; e < 8; e++) {
                float zz = (e < 4) ? z0[e] : z1[e - 4];
                hh[e] = (short)f2bf(fmaxf(zz + bf2f((ushort)u8[e]) + bf2f((ushort)v8[e]), 0.f));
            }
            *(short8*)&h1[r][cg + g] = hh;
        }
    }
    __syncthreads();

    int wave = tid >> 6, lane = tid & 63;
    int m16 = lane & 15, quad = lane >> 4;

    // per-lane epilogue constants
    float eb2v[4], ew3v[4];
    const ushort* bbase[4];
#pragma unroll
    for (int nt = 0; nt < 4; nt++) {
        int col = wave * 64 + nt * 16 + m16;
        eb2v[nt] = eb2[col];
        ew3v[nt] = ew3[col];
        bbase[nt] = ew2T + col * HIDDEN;
    }

    // ---- GEMM2: (32 x 512) x (512 x 256), wave covers 64 cols; B reg double-buffer
    float4v acc2[2][4];
#pragma unroll
    for (int mt = 0; mt < 2; mt++)
#pragma unroll
        for (int nt = 0; nt < 4; nt++) acc2[mt][nt] = (float4v)(0.f);

    int kk0 = quad * 8;
    short8 bcur[4];
#pragma unroll
    for (int nt = 0; nt < 4; nt++) bcur[nt] = *(const short8*)(bbase[nt] + kk0);

#pragma unroll
    for (int it = 0; it < 16; ++it) {
        int kk = it * 32 + kk0;
        short8 bnext[4];
        if (it < 15) {
#pragma unroll
            for (int nt = 0; nt < 4; nt++) bnext[nt] = *(const short8*)(bbase[nt] + kk + 32);
        } else {
#pragma unroll
            for (int nt = 0; nt < 4; nt++) bnext[nt] = bcur[nt];
        }
        short8 a0 = *(const short8*)&h1[m16][kk];
        short8 a1 = *(const short8*)&h1[16 + m16][kk];
#pragma unroll
        for (int nt = 0; nt < 4; nt++) {
            acc2[0][nt] = __builtin_amdgcn_mfma_f32_16x16x32_bf16(a0, bcur[nt], acc2[0][nt], 0, 0, 0);
            acc2[1][nt] = __builtin_amdgcn_mfma_f32_16x16x32_bf16(a1, bcur[nt], acc2[1][nt], 0, 0, 0);
        }
#pragma unroll
        for (int nt = 0; nt < 4; nt++) bcur[nt] = bnext[nt];
    }

    // ---- fused relu + 256-dot via shfl-reduce over m16 lanes (bits 0..3)
#pragma unroll
    for (int mt = 0; mt < 2; mt++)
#pragma unroll
        for (int t = 0; t < 4; t++) {
            float s = 0.f;
#pragma unroll
            for (int nt = 0; nt < 4; nt++)
                s += fmaxf(acc2[mt][nt][t] + eb2v[nt], 0.f) * ew3v[nt];
            s += __shfl_xor(s, 1);
            s += __shfl_xor(s, 2);
            s += __shfl_xor(s, 4);
            s += __shfl_xor(s, 8);
            if (m16 == 0) part[mt * 16 + quad * 4 + t][wave] = s;
        }
    __syncthreads();

    if (tid < MTILE) {
        float v = part[tid][0] + part[tid][1] + part[tid][2] + part[tid][3] + eb3[0];
        out_edges[blockIdx.x * MTILE + tid] = sigmoidf(v);
    }
}

extern "C" void kernel_launch(void* const* d_in, const int* in_sizes, int n_in,
                              void* d_out, int out_size, void* d_ws, size_t ws_size,
                              hipStream_t stream) {
    const float* z   = (const float*)d_in[0];
    const float* nw1 = (const float*)d_in[1];
    const float* nb1 = (const float*)d_in[2];
    const float* nw2 = (const float*)d_in[3];
    const float* nb2 = (const float*)d_in[4];
    const float* nw3 = (const float*)d_in[5];
    const float* nb3 = (const float*)d_in[6];
    const float* ew1 = (const float*)d_in[7];
    const float* eb1 = (const float*)d_in[8];
    const float* ew2 = (const float*)d_in[9];
    const float* eb2 = (const float*)d_in[10];
    const float* ew3 = (const float*)d_in[11];
    const float* eb3 = (const float*)d_in[12];

    char* ws = (char*)d_ws;
    float*  h1f  = (float*)(ws);                     // 128*512*4      = 262144
    ushort* h2b  = (ushort*)(ws + 262144);           // 128*512*2      = 131072
    ushort* nf   = (ushort*)(ws + 393216);           // 128*6400*2     = 1638400
    ushort* ew2T = (ushort*)(ws + 2031616);          // 256*512*2      = 262144
    ushort* wijT = (ushort*)(ws + 2293760);          // 1024*128*2     = 262144
    ushort* nw3T = (ushort*)(ws + 2555904);          // 6400*512*2     = 6553600
    float*  Zc   = (float*)(ws + 9109504);           // 128*512*4      = 262144
    ushort* UV   = (ushort*)(ws + 9371648);          // 6400*1024*2    = 13107200
                                                     // total 22478848 B (~21.4 MB)

    float* out_nodes = (float*)d_out;                // 128*6400
    float* out_edges = out_nodes + BATCH * NODE_OUT; // 128*1225

    // prep elements: 131072 + 131072 = 262144 = 1024*256
    k_prep<<<1024, 256, 0, stream>>>(ew1, ew2, ew2T, wijT);
    k_tr3<<<800, 256, 0, stream>>>(nw3, nw3T);
    k_zc<<<BATCH, 512, 0, stream>>>(z, ew1, eb1, Zc);
    k_node_h1<<<BATCH, 512, 0, stream>>>(z, nw1, nb1, h1f);
    k_node_h2<<<BATCH, 512, 0, stream>>>(h1f, nw2, nb2, h2b);
    k_node_out_mfma<<<100, 256, 0, stream>>>(h2b, nw3T, nb3, out_nodes, nf);
    k_uv<<<400, 256, 0, stream>>>(nf, wijT, UV);
    k_edge2<<<(BATCH * NPAIRS) / MTILE, 256, 0, stream>>>(Zc, UV, ew2T, ew3,
                                                          eb2, eb3, out_edges);
}

// Round 5
// 365.530 us; speedup vs baseline: 1.8717x; 1.0686x over previous
//
#include <hip/hip_runtime.h>
#include <math.h>

#define LATENT 256
#define HIDDEN 512
#define NODE_F 128
#define MAX_NODES 50
#define NPAIRS 1225        // 50*49/2
#define BATCH 128
#define NODE_OUT 6400      // MAX_NODES*NODE_F
#define MTILE 32           // edge rows per block

typedef __attribute__((ext_vector_type(8))) short short8;
typedef __attribute__((ext_vector_type(4))) float float4v;

__device__ __forceinline__ float bf2f(ushort u) {
    union { unsigned int i; float f; } v; v.i = ((unsigned int)u) << 16; return v.f;
}
__device__ __forceinline__ ushort f2bf(float f) {
    union { unsigned int i; float f; } v; v.f = f;
    unsigned int r = v.i + 0x7fffu + ((v.i >> 16) & 1u);   // RNE
    return (ushort)(r >> 16);
}
__device__ __forceinline__ float sigmoidf(float x) {
    return 1.0f / (1.0f + __expf(-x));
}

// ================= fused prep kernel: 4 independent jobs, one launch =================
// blocks [0,800)        : nw3T[n][k] = bf16(nw3[k][n])          (LDS-tiled transpose)
// blocks [800,1824)     : ew2T / wijT bf16 transposes
// blocks [1824,2080)    : Zc = z @ W_z + eb1                     (fp32)
// blocks [2080,2336)    : h1f = relu(z @ nw1 + nb1)              (fp32)
#define TR3_B0   0
#define PREP_B0  800
#define ZC_B0    1824
#define H1_B0    2080
#define PREPK_NB 2336

__global__ __launch_bounds__(256) void k_prep_all(
    const float* __restrict__ nw3, ushort* __restrict__ nw3T,
    const float* __restrict__ ew1, const float* __restrict__ ew2,
    ushort* __restrict__ ew2T, ushort* __restrict__ wijT,
    const float* __restrict__ z, const float* __restrict__ eb1,
    float* __restrict__ Zc,
    const float* __restrict__ nw1, const float* __restrict__ nb1,
    float* __restrict__ h1f)
{
    __shared__ float smem[64 * 65];
    int b = blockIdx.x;
    int tid = threadIdx.x;

    if (b < PREP_B0) {
        // ---- nw3 transpose, 64x64 tiles (8 k-tiles x 100 n-tiles)
        int bb = b - TR3_B0;
        int k0 = (bb & 7) * 64;
        int n0 = (bb >> 3) * 64;
        int tx = tid & 63, ty = tid >> 6;   // 64 x 4
#pragma unroll
        for (int r = 0; r < 16; r++) {
            int row = r * 4 + ty;
            smem[row * 65 + tx] = nw3[(k0 + row) * NODE_OUT + n0 + tx];
        }
        __syncthreads();
#pragma unroll
        for (int c = 0; c < 16; c++) {
            int n = c * 4 + ty;
            nw3T[(size_t)(n0 + n) * HIDDEN + k0 + tx] = f2bf(smem[tx * 65 + n]);
        }
    } else if (b < ZC_B0) {
        int t = (b - PREP_B0) * 256 + tid;
        if (t < 256 * 512) {
            int n = t >> 9, k = t & 511;
            ew2T[t] = f2bf(ew2[k * 256 + n]);
        } else {
            int u = t - 256 * 512;          // < 1024*128
            int n = u >> 7, k = u & 127;
            float s = (n < 512) ? ew1[(256 + k) * 512 + n] : ew1[(384 + k) * 512 + (n - 512)];
            wijT[u] = f2bf(s);
        }
    } else if (b < H1_B0) {
        // ---- Zc: 256 blocks, r = b2>>1, cols half*256+tid
        int b2 = b - ZC_B0;
        int r = b2 >> 1, o = (b2 & 1) * 256 + tid;
        float* zs = smem;
        zs[tid] = z[r * LATENT + tid];
        __syncthreads();
        float acc = 0.f;
#pragma unroll 8
        for (int k = 0; k < LATENT; k++) acc += zs[k] * ew1[k * HIDDEN + o];
        Zc[r * HIDDEN + o] = acc + eb1[o];
    } else {
        // ---- node h1: 256 blocks
        int b2 = b - H1_B0;
        int r = b2 >> 1, o = (b2 & 1) * 256 + tid;
        float* zs = smem;
        zs[tid] = z[r * LATENT + tid];
        __syncthreads();
        float acc = 0.f;
#pragma unroll 8
        for (int k = 0; k < LATENT; k++) acc += zs[k] * nw1[k * HIDDEN + o];
        acc += nb1[o];
        h1f[r * HIDDEN + o] = fmaxf(acc, 0.f);
    }
}

// ---------------- node MLP layer 2: h2b = bf16(relu(h1 @ nw2 + nb2)), 256 blocks
__global__ __launch_bounds__(256) void k_node_h2(
    const float* __restrict__ h1, const float* __restrict__ nw2,
    const float* __restrict__ nb2, ushort* __restrict__ h2b)
{
    __shared__ float hs[HIDDEN];
    int r = blockIdx.x >> 1;
    int o = (blockIdx.x & 1) * 256 + threadIdx.x;
    hs[threadIdx.x] = h1[r * HIDDEN + threadIdx.x];
    hs[threadIdx.x + 256] = h1[r * HIDDEN + threadIdx.x + 256];
    __syncthreads();
    float acc = 0.f;
#pragma unroll 8
    for (int k = 0; k < HIDDEN; k++) acc += hs[k] * nw2[k * HIDDEN + o];
    acc += nb2[o];
    h2b[r * HIDDEN + o] = f2bf(fmaxf(acc, 0.f));
}

// ---------------- node layer 3 via MFMA: grid 400 = 100 n-tiles(64) x 4 m-tiles(32)
__global__ __launch_bounds__(256, 4) void k_node_out_mfma(
    const ushort* __restrict__ h2b, const ushort* __restrict__ nw3T,
    const float* __restrict__ nb3, float* __restrict__ node_probs,
    ushort* __restrict__ node_feats)
{
    int tid = threadIdx.x;
    int wave = tid >> 6, lane = tid & 63;
    int m16 = lane & 15, quad = lane >> 4;
    int n0 = (blockIdx.x >> 2) * 64;
    int m0 = (blockIdx.x & 3) * 32;
    int col = n0 + wave * 16 + m16;

    float4v acc[2];
    acc[0] = (float4v)(0.f); acc[1] = (float4v)(0.f);

    const ushort* bb = nw3T + (size_t)col * HIDDEN;
    const ushort* a0p = h2b + (m0 + m16) * HIDDEN;
    const ushort* a1p = h2b + (m0 + 16 + m16) * HIDDEN;
#pragma unroll
    for (int it = 0; it < 16; ++it) {
        int kk = it * 32 + quad * 8;
        short8 b = *(const short8*)(bb + kk);
        short8 a0 = *(const short8*)(a0p + kk);
        short8 a1 = *(const short8*)(a1p + kk);
        acc[0] = __builtin_amdgcn_mfma_f32_16x16x32_bf16(a0, b, acc[0], 0, 0, 0);
        acc[1] = __builtin_amdgcn_mfma_f32_16x16x32_bf16(a1, b, acc[1], 0, 0, 0);
    }
    float bias = nb3[col];
#pragma unroll
    for (int mt = 0; mt < 2; mt++)
#pragma unroll
        for (int t = 0; t < 4; t++) {
            int row = m0 + mt * 16 + quad * 4 + t;
            float v = acc[mt][t] + bias;
            node_probs[(size_t)row * NODE_OUT + col] = sigmoidf(v);
            node_feats[(size_t)row * NODE_OUT + col] = f2bf(v);
        }
}

// ---------------- UV = node_feats @ [W_i|W_j]   (6400 x 1024, bf16 out)
__global__ __launch_bounds__(256, 4) void k_uv(
    const ushort* __restrict__ nf, const ushort* __restrict__ wijT,
    ushort* __restrict__ UV)
{
    int tid = threadIdx.x;
    int wave = tid >> 6, lane = tid & 63;
    int m16 = lane & 15, quad = lane >> 4;
    int bm = blockIdx.x >> 1, bn = blockIdx.x & 1;
    int base = bn * 512 + wave * 128;

    float4v acc[2][8];
#pragma unroll
    for (int mt = 0; mt < 2; mt++)
#pragma unroll
        for (int nt = 0; nt < 8; nt++) acc[mt][nt] = (float4v)(0.f);

#pragma unroll
    for (int k0 = 0; k0 < NODE_F; k0 += 32) {
        int kk = k0 + quad * 8;
        short8 a0 = *(const short8*)(nf + (bm * 32 + m16) * NODE_F + kk);
        short8 a1 = *(const short8*)(nf + (bm * 32 + 16 + m16) * NODE_F + kk);
#pragma unroll
        for (int nt = 0; nt < 8; nt++) {
            int n = base + nt * 16 + m16;
            short8 b = *(const short8*)(wijT + n * NODE_F + kk);
            acc[0][nt] = __builtin_amdgcn_mfma_f32_16x16x32_bf16(a0, b, acc[0][nt], 0, 0, 0);
            acc[1][nt] = __builtin_amdgcn_mfma_f32_16x16x32_bf16(a1, b, acc[1][nt], 0, 0, 0);
        }
    }
#pragma unroll
    for (int nt = 0; nt < 8; nt++) {
        int colg = base + nt * 16 + m16;
#pragma unroll
        for (int mt = 0; mt < 2; mt++)
#pragma unroll
            for (int t = 0; t < 4; t++) {
                int rr = bm * 32 + mt * 16 + quad * 4 + t;
                UV[(size_t)rr * 1024 + colg] = f2bf(acc[mt][nt][t]);
            }
    }
}

// ---------------- fused edge: h1 = relu(Zc[b]+U[i]+V[j]) -> GEMM2 -> dot -> sigmoid
__global__ __launch_bounds__(256, 4) void k_edge2(
    const float* __restrict__ Zc, const ushort* __restrict__ UV,
    const ushort* __restrict__ ew2T, const float* __restrict__ ew3,
    const float* __restrict__ eb2, const float* __restrict__ eb3,
    float* __restrict__ out_edges)
{
    __shared__ __align__(16) ushort h1[MTILE][HIDDEN + 8];   // 33,280 B
    __shared__ float part[MTILE][4];
    __shared__ int zo[MTILE], uo[MTILE], vo[MTILE];

    int tid = threadIdx.x;
    if (tid < MTILE) {
        int r = blockIdx.x * MTILE + tid;
        int b = r / NPAIRS;
        int p = r - b * NPAIRS;
        int i = 0, off = 0;
        while (p - off >= MAX_NODES - 1 - i) { off += MAX_NODES - 1 - i; ++i; }
        int j = i + 1 + (p - off);
        zo[tid] = b * HIDDEN;
        uo[tid] = (b * MAX_NODES + i) * 1024;
        vo[tid] = (b * MAX_NODES + j) * 1024 + 512;
    }
    __syncthreads();

    // ---- assemble h1 tile: each thread 1 row x 64 cols; batch loads 4 chunks deep
    {
        int r = tid >> 3, cg = (tid & 7) * 64;
        const float*  zp = Zc + zo[r] + cg;
        const ushort* up = UV + uo[r] + cg;
        const ushort* vp = UV + vo[r] + cg;
#pragma unroll
        for (int h = 0; h < 2; h++) {
            short8 ub[4], vb[4];
            float4v za[4], zbv[4];
#pragma unroll
            for (int g = 0; g < 4; g++) {
                int c = h * 32 + g * 8;
                ub[g]  = *(const short8*)(up + c);
                vb[g]  = *(const short8*)(vp + c);
                za[g]  = *(const float4v*)(zp + c);
                zbv[g] = *(const float4v*)(zp + c + 4);
            }
#pragma unroll
            for (int g = 0; g < 4; g++) {
                short8 hh;
#pragma unroll
                for (int e = 0; e < 8; e++) {
                    float zz = (e < 4) ? za[g][e] : zbv[g][e - 4];
                    hh[e] = (short)f2bf(fmaxf(zz + bf2f((ushort)ub[g][e]) + bf2f((ushort)vb[g][e]), 0.f));
                }
                *(short8*)&h1[r][cg + h * 32 + g * 8] = hh;
            }
        }
    }
    __syncthreads();

    int wave = tid >> 6, lane = tid & 63;
    int m16 = lane & 15, quad = lane >> 4;

    // per-lane epilogue constants
    float eb2v[4], ew3v[4];
    const ushort* bbase[4];
#pragma unroll
    for (int nt = 0; nt < 4; nt++) {
        int col = wave * 64 + nt * 16 + m16;
        eb2v[nt] = eb2[col];
        ew3v[nt] = ew3[col];
        bbase[nt] = ew2T + col * HIDDEN;
    }

    // ---- GEMM2: (32 x 512) x (512 x 256); full unroll, compiler hoists B loads
    float4v acc2[2][4];
#pragma unroll
    for (int mt = 0; mt < 2; mt++)
#pragma unroll
        for (int nt = 0; nt < 4; nt++) acc2[mt][nt] = (float4v)(0.f);

    int kk0 = quad * 8;
#pragma unroll
    for (int it = 0; it < 16; ++it) {
        int kk = it * 32 + kk0;
        short8 b0 = *(const short8*)(bbase[0] + kk);
        short8 b1 = *(const short8*)(bbase[1] + kk);
        short8 b2 = *(const short8*)(bbase[2] + kk);
        short8 b3 = *(const short8*)(bbase[3] + kk);
        short8 a0 = *(const short8*)&h1[m16][kk];
        short8 a1 = *(const short8*)&h1[16 + m16][kk];
        acc2[0][0] = __builtin_amdgcn_mfma_f32_16x16x32_bf16(a0, b0, acc2[0][0], 0, 0, 0);
        acc2[1][0] = __builtin_amdgcn_mfma_f32_16x16x32_bf16(a1, b0, acc2[1][0], 0, 0, 0);
        acc2[0][1] = __builtin_amdgcn_mfma_f32_16x16x32_bf16(a0, b1, acc2[0][1], 0, 0, 0);
        acc2[1][1] = __builtin_amdgcn_mfma_f32_16x16x32_bf16(a1, b1, acc2[1][1], 0, 0, 0);
        acc2[0][2] = __builtin_amdgcn_mfma_f32_16x16x32_bf16(a0, b2, acc2[0][2], 0, 0, 0);
        acc2[1][2] = __builtin_amdgcn_mfma_f32_16x16x32_bf16(a1, b2, acc2[1][2], 0, 0, 0);
        acc2[0][3] = __builtin_amdgcn_mfma_f32_16x16x32_bf16(a0, b3, acc2[0][3], 0, 0, 0);
        acc2[1][3] = __builtin_amdgcn_mfma_f32_16x16x32_bf16(a1, b3, acc2[1][3], 0, 0, 0);
    }

    // ---- fused relu + 256-dot via shfl-reduce over m16 lanes
#pragma unroll
    for (int mt = 0; mt < 2; mt++)
#pragma unroll
        for (int t = 0; t < 4; t++) {
            float s = 0.f;
#pragma unroll
            for (int nt = 0; nt < 4; nt++)
                s += fmaxf(acc2[mt][nt][t] + eb2v[nt], 0.f) * ew3v[nt];
            s += __shfl_xor(s, 1);
            s += __shfl_xor(s, 2);
            s += __shfl_xor(s, 4);
            s += __shfl_xor(s, 8);
            if (m16 == 0) part[mt * 16 + quad * 4 + t][wave] = s;
        }
    __syncthreads();

    if (tid < MTILE) {
        float v = part[tid][0] + part[tid][1] + part[tid][2] + part[tid][3] + eb3[0];
        out_edges[blockIdx.x * MTILE + tid] = sigmoidf(v);
    }
}

extern "C" void kernel_launch(void* const* d_in, const int* in_sizes, int n_in,
                              void* d_out, int out_size, void* d_ws, size_t ws_size,
                              hipStream_t stream) {
    const float* z   = (const float*)d_in[0];
    const float* nw1 = (const float*)d_in[1];
    const float* nb1 = (const float*)d_in[2];
    const float* nw2 = (const float*)d_in[3];
    const float* nb2 = (const float*)d_in[4];
    const float* nw3 = (const float*)d_in[5];
    const float* nb3 = (const float*)d_in[6];
    const float* ew1 = (const float*)d_in[7];
    const float* eb1 = (const float*)d_in[8];
    const float* ew2 = (const float*)d_in[9];
    const float* eb2 = (const float*)d_in[10];
    const float* ew3 = (const float*)d_in[11];
    const float* eb3 = (const float*)d_in[12];

    char* ws = (char*)d_ws;
    float*  h1f  = (float*)(ws);                     // 128*512*4      = 262144
    ushort* h2b  = (ushort*)(ws + 262144);           // 128*512*2      = 131072
    ushort* nf   = (ushort*)(ws + 393216);           // 128*6400*2     = 1638400
    ushort* ew2T = (ushort*)(ws + 2031616);          // 256*512*2      = 262144
    ushort* wijT = (ushort*)(ws + 2293760);          // 1024*128*2     = 262144
    ushort* nw3T = (ushort*)(ws + 2555904);          // 6400*512*2     = 6553600
    float*  Zc   = (float*)(ws + 9109504);           // 128*512*4      = 262144
    ushort* UV   = (ushort*)(ws + 9371648);          // 6400*1024*2    = 13107200
                                                     // total 22478848 B (~21.4 MB)

    float* out_nodes = (float*)d_out;                // 128*6400
    float* out_edges = out_nodes + BATCH * NODE_OUT; // 128*1225

    k_prep_all<<<PREPK_NB, 256, 0, stream>>>(nw3, nw3T, ew1, ew2, ew2T, wijT,
                                             z, eb1, Zc, nw1, nb1, h1f);
    k_node_h2<<<256, 256, 0, stream>>>(h1f, nw2, nb2, h2b);
    k_node_out_mfma<<<400, 256, 0, stream>>>(h2b, nw3T, nb3, out_nodes, nf);
    k_uv<<<400, 256, 0, stream>>>(nf, wijT, UV);
    k_edge2<<<(BATCH * NPAIRS) / MTILE, 256, 0, stream>>>(Zc, UV, ew2T, ew3,
                                                          eb2, eb3, out_edges);
}

// Round 6
// 307.634 us; speedup vs baseline: 2.2240x; 1.1882x over previous
//
#include <hip/hip_runtime.h>
#include <math.h>

#define LATENT 256
#define HIDDEN 512
#define NODE_F 128
#define MAX_NODES 50
#define NPAIRS 1225        // 50*49/2
#define BATCH 128
#define NODE_OUT 6400      // MAX_NODES*NODE_F
#define MTILE 32           // edge rows per block
#define PTILES 39          // ceil(1225/32)

typedef __attribute__((ext_vector_type(8))) short short8;
typedef __attribute__((ext_vector_type(4))) float float4v;

__device__ __forceinline__ float bf2f(ushort u) {
    union { unsigned int i; float f; } v; v.i = ((unsigned int)u) << 16; return v.f;
}
__device__ __forceinline__ ushort f2bf(float f) {
    union { unsigned int i; float f; } v; v.f = f;
    unsigned int r = v.i + 0x7fffu + ((v.i >> 16) & 1u);   // RNE
    return (ushort)(r >> 16);
}
__device__ __forceinline__ float sigmoidf(float x) {
    return 1.0f / (1.0f + __expf(-x));
}

// ================= fused prep kernel: 4 independent jobs, one launch =================
#define TR3_B0   0
#define PREP_B0  800
#define ZC_B0    1824
#define H1_B0    2080
#define PREPK_NB 2336

__global__ __launch_bounds__(256) void k_prep_all(
    const float* __restrict__ nw3, ushort* __restrict__ nw3T,
    const float* __restrict__ ew1, const float* __restrict__ ew2,
    ushort* __restrict__ ew2T, ushort* __restrict__ wijT,
    const float* __restrict__ z, const float* __restrict__ eb1,
    float* __restrict__ Zc,
    const float* __restrict__ nw1, const float* __restrict__ nb1,
    float* __restrict__ h1f)
{
    __shared__ float smem[64 * 65];
    int b = blockIdx.x;
    int tid = threadIdx.x;

    if (b < PREP_B0) {
        // ---- nw3 transpose, 64x64 tiles (8 k-tiles x 100 n-tiles)
        int bb = b - TR3_B0;
        int k0 = (bb & 7) * 64;
        int n0 = (bb >> 3) * 64;
        int tx = tid & 63, ty = tid >> 6;   // 64 x 4
#pragma unroll
        for (int r = 0; r < 16; r++) {
            int row = r * 4 + ty;
            smem[row * 65 + tx] = nw3[(k0 + row) * NODE_OUT + n0 + tx];
        }
        __syncthreads();
#pragma unroll
        for (int c = 0; c < 16; c++) {
            int n = c * 4 + ty;
            nw3T[(size_t)(n0 + n) * HIDDEN + k0 + tx] = f2bf(smem[tx * 65 + n]);
        }
    } else if (b < ZC_B0) {
        int t = (b - PREP_B0) * 256 + tid;
        if (t < 256 * 512) {
            int n = t >> 9, k = t & 511;
            ew2T[t] = f2bf(ew2[k * 256 + n]);
        } else {
            int u = t - 256 * 512;          // < 1024*128
            int n = u >> 7, k = u & 127;
            float s = (n < 512) ? ew1[(256 + k) * 512 + n] : ew1[(384 + k) * 512 + (n - 512)];
            wijT[u] = f2bf(s);
        }
    } else if (b < H1_B0) {
        // ---- Zc = z @ W_z + eb1
        int b2 = b - ZC_B0;
        int r = b2 >> 1, o = (b2 & 1) * 256 + tid;
        float* zs = smem;
        zs[tid] = z[r * LATENT + tid];
        __syncthreads();
        float acc = 0.f;
#pragma unroll 8
        for (int k = 0; k < LATENT; k++) acc += zs[k] * ew1[k * HIDDEN + o];
        Zc[r * HIDDEN + o] = acc + eb1[o];
    } else {
        // ---- node h1
        int b2 = b - H1_B0;
        int r = b2 >> 1, o = (b2 & 1) * 256 + tid;
        float* zs = smem;
        zs[tid] = z[r * LATENT + tid];
        __syncthreads();
        float acc = 0.f;
#pragma unroll 8
        for (int k = 0; k < LATENT; k++) acc += zs[k] * nw1[k * HIDDEN + o];
        acc += nb1[o];
        h1f[r * HIDDEN + o] = fmaxf(acc, 0.f);
    }
}

// ---------------- node MLP layer 2: h2b = bf16(relu(h1 @ nw2 + nb2)), 256 blocks
__global__ __launch_bounds__(256) void k_node_h2(
    const float* __restrict__ h1, const float* __restrict__ nw2,
    const float* __restrict__ nb2, ushort* __restrict__ h2b)
{
    __shared__ float hs[HIDDEN];
    int r = blockIdx.x >> 1;
    int o = (blockIdx.x & 1) * 256 + threadIdx.x;
    hs[threadIdx.x] = h1[r * HIDDEN + threadIdx.x];
    hs[threadIdx.x + 256] = h1[r * HIDDEN + threadIdx.x + 256];
    __syncthreads();
    float acc = 0.f;
#pragma unroll 8
    for (int k = 0; k < HIDDEN; k++) acc += hs[k] * nw2[k * HIDDEN + o];
    acc += nb2[o];
    h2b[r * HIDDEN + o] = f2bf(fmaxf(acc, 0.f));
}

// ---------------- node layer 3 via MFMA: grid 400 = 100 n-tiles(64) x 4 m-tiles(32)
__global__ __launch_bounds__(256, 4) void k_node_out_mfma(
    const ushort* __restrict__ h2b, const ushort* __restrict__ nw3T,
    const float* __restrict__ nb3, float* __restrict__ node_probs,
    ushort* __restrict__ node_feats)
{
    int tid = threadIdx.x;
    int wave = tid >> 6, lane = tid & 63;
    int m16 = lane & 15, quad = lane >> 4;
    int n0 = (blockIdx.x >> 2) * 64;
    int m0 = (blockIdx.x & 3) * 32;
    int col = n0 + wave * 16 + m16;

    float4v acc[2];
    acc[0] = (float4v)(0.f); acc[1] = (float4v)(0.f);

    const ushort* bb = nw3T + (size_t)col * HIDDEN;
    const ushort* a0p = h2b + (m0 + m16) * HIDDEN;
    const ushort* a1p = h2b + (m0 + 16 + m16) * HIDDEN;
#pragma unroll
    for (int it = 0; it < 16; ++it) {
        int kk = it * 32 + quad * 8;
        short8 b = *(const short8*)(bb + kk);
        short8 a0 = *(const short8*)(a0p + kk);
        short8 a1 = *(const short8*)(a1p + kk);
        acc[0] = __builtin_amdgcn_mfma_f32_16x16x32_bf16(a0, b, acc[0], 0, 0, 0);
        acc[1] = __builtin_amdgcn_mfma_f32_16x16x32_bf16(a1, b, acc[1], 0, 0, 0);
    }
    float bias = nb3[col];
#pragma unroll
    for (int mt = 0; mt < 2; mt++)
#pragma unroll
        for (int t = 0; t < 4; t++) {
            int row = m0 + mt * 16 + quad * 4 + t;
            float v = acc[mt][t] + bias;
            node_probs[(size_t)row * NODE_OUT + col] = sigmoidf(v);
            node_feats[(size_t)row * NODE_OUT + col] = f2bf(v);
        }
}

// ---------------- UV = node_feats @ [W_i|W_j]   (6400 x 1024, bf16 out)
__global__ __launch_bounds__(256, 4) void k_uv(
    const ushort* __restrict__ nf, const ushort* __restrict__ wijT,
    ushort* __restrict__ UV)
{
    int tid = threadIdx.x;
    int wave = tid >> 6, lane = tid & 63;
    int m16 = lane & 15, quad = lane >> 4;
    int bm = blockIdx.x >> 1, bn = blockIdx.x & 1;
    int base = bn * 512 + wave * 128;

    float4v acc[2][8];
#pragma unroll
    for (int mt = 0; mt < 2; mt++)
#pragma unroll
        for (int nt = 0; nt < 8; nt++) acc[mt][nt] = (float4v)(0.f);

#pragma unroll
    for (int k0 = 0; k0 < NODE_F; k0 += 32) {
        int kk = k0 + quad * 8;
        short8 a0 = *(const short8*)(nf + (bm * 32 + m16) * NODE_F + kk);
        short8 a1 = *(const short8*)(nf + (bm * 32 + 16 + m16) * NODE_F + kk);
#pragma unroll
        for (int nt = 0; nt < 8; nt++) {
            int n = base + nt * 16 + m16;
            short8 b = *(const short8*)(wijT + n * NODE_F + kk);
            acc[0][nt] = __builtin_amdgcn_mfma_f32_16x16x32_bf16(a0, b, acc[0][nt], 0, 0, 0);
            acc[1][nt] = __builtin_amdgcn_mfma_f32_16x16x32_bf16(a1, b, acc[1][nt], 0, 0, 0);
        }
    }
#pragma unroll
    for (int nt = 0; nt < 8; nt++) {
        int colg = base + nt * 16 + m16;
#pragma unroll
        for (int mt = 0; mt < 2; mt++)
#pragma unroll
            for (int t = 0; t < 4; t++) {
                int rr = bm * 32 + mt * 16 + quad * 4 + t;
                UV[(size_t)rr * 1024 + colg] = f2bf(acc[mt][nt][t]);
            }
    }
}

// ---------------- fused edge, per-batch tiling:
// grid = BATCH * PTILES; block handles 32 pairs of one batch b.
// h1 = relu(Zc[b] + U[i] + V[j]) assembled with fully-coalesced row reads.
__global__ __launch_bounds__(256, 4) void k_edge3(
    const float* __restrict__ Zc, const ushort* __restrict__ UV,
    const ushort* __restrict__ ew2T, const float* __restrict__ ew3,
    const float* __restrict__ eb2, const float* __restrict__ eb3,
    float* __restrict__ out_edges)
{
    __shared__ __align__(16) ushort h1[MTILE][HIDDEN + 8];   // 33,280 B
    __shared__ float part[MTILE][4];
    __shared__ int uo[MTILE], vo[MTILE];

    int blk = blockIdx.x;
    int b   = blk / PTILES;
    int t0  = (blk - b * PTILES) * MTILE;    // first pair index in batch b

    int tid = threadIdx.x;
    if (tid < MTILE) {
        int p = t0 + tid;
        if (p >= NPAIRS) p = NPAIRS - 1;     // tail: duplicate last pair (write masked)
        int i = 0, off = 0;
        while (p - off >= MAX_NODES - 1 - i) { off += MAX_NODES - 1 - i; ++i; }
        int j = i + 1 + (p - off);
        uo[tid] = (b * MAX_NODES + i) * 1024;
        vo[tid] = (b * MAX_NODES + j) * 1024 + 512;
    }

    int wave = tid >> 6, lane = tid & 63;

    // each lane's 8-col slice of Zc[b] (coalesced 2KB wave read), reused for 8 rows
    int c8 = lane * 8;
    float4v zA = *(const float4v*)(Zc + b * HIDDEN + c8);
    float4v zB = *(const float4v*)(Zc + b * HIDDEN + c8 + 4);
    __syncthreads();

    // ---- assemble h1: wave handles rows [wave*8, wave*8+8); per row lane covers cols [8l,8l+8)
    // U/V row reads are contiguous 1KB per wave-load (16 cache lines, was 64).
#pragma unroll
    for (int rr = 0; rr < 8; rr++) {
        int r = wave * 8 + rr;
        short8 u8 = *(const short8*)(UV + uo[r] + c8);
        short8 v8 = *(const short8*)(UV + vo[r] + c8);
        short8 hh;
#pragma unroll
        for (int e = 0; e < 8; e++) {
            float zz = (e < 4) ? zA[e] : zB[e - 4];
            hh[e] = (short)f2bf(fmaxf(zz + bf2f((ushort)u8[e]) + bf2f((ushort)v8[e]), 0.f));
        }
        *(short8*)&h1[r][c8] = hh;
    }
    __syncthreads();

    int m16 = lane & 15, quad = lane >> 4;

    // per-lane epilogue constants
    float eb2v[4], ew3v[4];
    const ushort* bbase[4];
#pragma unroll
    for (int nt = 0; nt < 4; nt++) {
        int col = wave * 64 + nt * 16 + m16;
        eb2v[nt] = eb2[col];
        ew3v[nt] = ew3[col];
        bbase[nt] = ew2T + col * HIDDEN;
    }

    // ---- GEMM2: (32 x 512) x (512 x 256); wave covers 64 cols
    float4v acc2[2][4];
#pragma unroll
    for (int mt = 0; mt < 2; mt++)
#pragma unroll
        for (int nt = 0; nt < 4; nt++) acc2[mt][nt] = (float4v)(0.f);

    int kk0 = quad * 8;
#pragma unroll
    for (int it = 0; it < 16; ++it) {
        int kk = it * 32 + kk0;
        short8 b0 = *(const short8*)(bbase[0] + kk);
        short8 b1 = *(const short8*)(bbase[1] + kk);
        short8 b2 = *(const short8*)(bbase[2] + kk);
        short8 b3 = *(const short8*)(bbase[3] + kk);
        short8 a0 = *(const short8*)&h1[m16][kk];
        short8 a1 = *(const short8*)&h1[16 + m16][kk];
        acc2[0][0] = __builtin_amdgcn_mfma_f32_16x16x32_bf16(a0, b0, acc2[0][0], 0, 0, 0);
        acc2[1][0] = __builtin_amdgcn_mfma_f32_16x16x32_bf16(a1, b0, acc2[1][0], 0, 0, 0);
        acc2[0][1] = __builtin_amdgcn_mfma_f32_16x16x32_bf16(a0, b1, acc2[0][1], 0, 0, 0);
        acc2[1][1] = __builtin_amdgcn_mfma_f32_16x16x32_bf16(a1, b1, acc2[1][1], 0, 0, 0);
        acc2[0][2] = __builtin_amdgcn_mfma_f32_16x16x32_bf16(a0, b2, acc2[0][2], 0, 0, 0);
        acc2[1][2] = __builtin_amdgcn_mfma_f32_16x16x32_bf16(a1, b2, acc2[1][2], 0, 0, 0);
        acc2[0][3] = __builtin_amdgcn_mfma_f32_16x16x32_bf16(a0, b3, acc2[0][3], 0, 0, 0);
        acc2[1][3] = __builtin_amdgcn_mfma_f32_16x16x32_bf16(a1, b3, acc2[1][3], 0, 0, 0);
    }

    // ---- fused relu + 256-dot via shfl-reduce over m16 lanes
#pragma unroll
    for (int mt = 0; mt < 2; mt++)
#pragma unroll
        for (int t = 0; t < 4; t++) {
            float s = 0.f;
#pragma unroll
            for (int nt = 0; nt < 4; nt++)
                s += fmaxf(acc2[mt][nt][t] + eb2v[nt], 0.f) * ew3v[nt];
            s += __shfl_xor(s, 1);
            s += __shfl_xor(s, 2);
            s += __shfl_xor(s, 4);
            s += __shfl_xor(s, 8);
            if (m16 == 0) part[mt * 16 + quad * 4 + t][wave] = s;
        }
    __syncthreads();

    if (tid < MTILE && t0 + tid < NPAIRS) {
        float v = part[tid][0] + part[tid][1] + part[tid][2] + part[tid][3] + eb3[0];
        out_edges[b * NPAIRS + t0 + tid] = sigmoidf(v);
    }
}

extern "C" void kernel_launch(void* const* d_in, const int* in_sizes, int n_in,
                              void* d_out, int out_size, void* d_ws, size_t ws_size,
                              hipStream_t stream) {
    const float* z   = (const float*)d_in[0];
    const float* nw1 = (const float*)d_in[1];
    const float* nb1 = (const float*)d_in[2];
    const float* nw2 = (const float*)d_in[3];
    const float* nb2 = (const float*)d_in[4];
    const float* nw3 = (const float*)d_in[5];
    const float* nb3 = (const float*)d_in[6];
    const float* ew1 = (const float*)d_in[7];
    const float* eb1 = (const float*)d_in[8];
    const float* ew2 = (const float*)d_in[9];
    const float* eb2 = (const float*)d_in[10];
    const float* ew3 = (const float*)d_in[11];
    const float* eb3 = (const float*)d_in[12];

    char* ws = (char*)d_ws;
    float*  h1f  = (float*)(ws);                     // 128*512*4      = 262144
    ushort* h2b  = (ushort*)(ws + 262144);           // 128*512*2      = 131072
    ushort* nf   = (ushort*)(ws + 393216);           // 128*6400*2     = 1638400
    ushort* ew2T = (ushort*)(ws + 2031616);          // 256*512*2      = 262144
    ushort* wijT = (ushort*)(ws + 2293760);          // 1024*128*2     = 262144
    ushort* nw3T = (ushort*)(ws + 2555904);          // 6400*512*2     = 6553600
    float*  Zc   = (float*)(ws + 9109504);           // 128*512*4      = 262144
    ushort* UV   = (ushort*)(ws + 9371648);          // 6400*1024*2    = 13107200
                                                     // total 22478848 B (~21.4 MB)

    float* out_nodes = (float*)d_out;                // 128*6400
    float* out_edges = out_nodes + BATCH * NODE_OUT; // 128*1225

    k_prep_all<<<PREPK_NB, 256, 0, stream>>>(nw3, nw3T, ew1, ew2, ew2T, wijT,
                                             z, eb1, Zc, nw1, nb1, h1f);
    k_node_h2<<<256, 256, 0, stream>>>(h1f, nw2, nb2, h2b);
    k_node_out_mfma<<<400, 256, 0, stream>>>(h2b, nw3T, nb3, out_nodes, nf);
    k_uv<<<400, 256, 0, stream>>>(nf, wijT, UV);
    k_edge3<<<BATCH * PTILES, 256, 0, stream>>>(Zc, UV, ew2T, ew3,
                                                eb2, eb3, out_edges);
}

// Round 7
// 260.052 us; speedup vs baseline: 2.6309x; 1.1830x over previous
//
#include <hip/hip_runtime.h>
#include <math.h>

#define LATENT 256
#define HIDDEN 512
#define NODE_F 128
#define MAX_NODES 50
#define NPAIRS 1225        // 50*49/2
#define BATCH 128
#define NODE_OUT 6400      // MAX_NODES*NODE_F
#define MTILE 64           // edge rows per block
#define PTILES 20          // ceil(1225/64)

typedef __attribute__((ext_vector_type(8))) short short8;
typedef __attribute__((ext_vector_type(4))) float float4v;

__device__ __forceinline__ float bf2f(ushort u) {
    union { unsigned int i; float f; } v; v.i = ((unsigned int)u) << 16; return v.f;
}
__device__ __forceinline__ ushort f2bf(float f) {
    union { unsigned int i; float f; } v; v.f = f;
    unsigned int r = v.i + 0x7fffu + ((v.i >> 16) & 1u);   // RNE
    return (ushort)(r >> 16);
}
__device__ __forceinline__ float sigmoidf(float x) {
    return 1.0f / (1.0f + __expf(-x));
}

// ================= fused prep kernel: 4 independent jobs, one launch =================
#define TR3_B0   0
#define PREP_B0  800
#define ZC_B0    1824
#define H1_B0    2080
#define PREPK_NB 2336

__global__ __launch_bounds__(256) void k_prep_all(
    const float* __restrict__ nw3, ushort* __restrict__ nw3T,
    const float* __restrict__ ew1, const float* __restrict__ ew2,
    ushort* __restrict__ ew2T, ushort* __restrict__ wijT,
    const float* __restrict__ z, const float* __restrict__ eb1,
    float* __restrict__ Zc,
    const float* __restrict__ nw1, const float* __restrict__ nb1,
    float* __restrict__ h1f)
{
    __shared__ float smem[64 * 65];
    int b = blockIdx.x;
    int tid = threadIdx.x;

    if (b < PREP_B0) {
        // ---- nw3 transpose, 64x64 tiles (8 k-tiles x 100 n-tiles)
        int bb = b - TR3_B0;
        int k0 = (bb & 7) * 64;
        int n0 = (bb >> 3) * 64;
        int tx = tid & 63, ty = tid >> 6;   // 64 x 4
#pragma unroll
        for (int r = 0; r < 16; r++) {
            int row = r * 4 + ty;
            smem[row * 65 + tx] = nw3[(k0 + row) * NODE_OUT + n0 + tx];
        }
        __syncthreads();
#pragma unroll
        for (int c = 0; c < 16; c++) {
            int n = c * 4 + ty;
            nw3T[(size_t)(n0 + n) * HIDDEN + k0 + tx] = f2bf(smem[tx * 65 + n]);
        }
    } else if (b < ZC_B0) {
        int t = (b - PREP_B0) * 256 + tid;
        if (t < 256 * 512) {
            int n = t >> 9, k = t & 511;
            ew2T[t] = f2bf(ew2[k * 256 + n]);
        } else {
            int u = t - 256 * 512;          // < 1024*128
            int n = u >> 7, k = u & 127;
            float s = (n < 512) ? ew1[(256 + k) * 512 + n] : ew1[(384 + k) * 512 + (n - 512)];
            wijT[u] = f2bf(s);
        }
    } else if (b < H1_B0) {
        // ---- Zc = z @ W_z + eb1
        int b2 = b - ZC_B0;
        int r = b2 >> 1, o = (b2 & 1) * 256 + tid;
        float* zs = smem;
        zs[tid] = z[r * LATENT + tid];
        __syncthreads();
        float acc = 0.f;
#pragma unroll 8
        for (int k = 0; k < LATENT; k++) acc += zs[k] * ew1[k * HIDDEN + o];
        Zc[r * HIDDEN + o] = acc + eb1[o];
    } else {
        // ---- node h1
        int b2 = b - H1_B0;
        int r = b2 >> 1, o = (b2 & 1) * 256 + tid;
        float* zs = smem;
        zs[tid] = z[r * LATENT + tid];
        __syncthreads();
        float acc = 0.f;
#pragma unroll 8
        for (int k = 0; k < LATENT; k++) acc += zs[k] * nw1[k * HIDDEN + o];
        acc += nb1[o];
        h1f[r * HIDDEN + o] = fmaxf(acc, 0.f);
    }
}

// ---------------- node MLP layer 2: h2b = bf16(relu(h1 @ nw2 + nb2)), 256 blocks
__global__ __launch_bounds__(256) void k_node_h2(
    const float* __restrict__ h1, const float* __restrict__ nw2,
    const float* __restrict__ nb2, ushort* __restrict__ h2b)
{
    __shared__ float hs[HIDDEN];
    int r = blockIdx.x >> 1;
    int o = (blockIdx.x & 1) * 256 + threadIdx.x;
    hs[threadIdx.x] = h1[r * HIDDEN + threadIdx.x];
    hs[threadIdx.x + 256] = h1[r * HIDDEN + threadIdx.x + 256];
    __syncthreads();
    float acc = 0.f;
#pragma unroll 8
    for (int k = 0; k < HIDDEN; k++) acc += hs[k] * nw2[k * HIDDEN + o];
    acc += nb2[o];
    h2b[r * HIDDEN + o] = f2bf(fmaxf(acc, 0.f));
}

// ---------------- node layer 3 via MFMA: grid 400 = 100 n-tiles(64) x 4 m-tiles(32)
__global__ __launch_bounds__(256, 4) void k_node_out_mfma(
    const ushort* __restrict__ h2b, const ushort* __restrict__ nw3T,
    const float* __restrict__ nb3, float* __restrict__ node_probs,
    ushort* __restrict__ node_feats)
{
    int tid = threadIdx.x;
    int wave = tid >> 6, lane = tid & 63;
    int m16 = lane & 15, quad = lane >> 4;
    int n0 = (blockIdx.x >> 2) * 64;
    int m0 = (blockIdx.x & 3) * 32;
    int col = n0 + wave * 16 + m16;

    float4v acc[2];
    acc[0] = (float4v)(0.f); acc[1] = (float4v)(0.f);

    const ushort* bb = nw3T + (size_t)col * HIDDEN;
    const ushort* a0p = h2b + (m0 + m16) * HIDDEN;
    const ushort* a1p = h2b + (m0 + 16 + m16) * HIDDEN;
#pragma unroll
    for (int it = 0; it < 16; ++it) {
        int kk = it * 32 + quad * 8;
        short8 b = *(const short8*)(bb + kk);
        short8 a0 = *(const short8*)(a0p + kk);
        short8 a1 = *(const short8*)(a1p + kk);
        acc[0] = __builtin_amdgcn_mfma_f32_16x16x32_bf16(a0, b, acc[0], 0, 0, 0);
        acc[1] = __builtin_amdgcn_mfma_f32_16x16x32_bf16(a1, b, acc[1], 0, 0, 0);
    }
    float bias = nb3[col];
#pragma unroll
    for (int mt = 0; mt < 2; mt++)
#pragma unroll
        for (int t = 0; t < 4; t++) {
            int row = m0 + mt * 16 + quad * 4 + t;
            float v = acc[mt][t] + bias;
            node_probs[(size_t)row * NODE_OUT + col] = sigmoidf(v);
            node_feats[(size_t)row * NODE_OUT + col] = f2bf(v);
        }
}

// ---------------- UV = node_feats @ [W_i|W_j]   (6400 x 1024, bf16 out)
__global__ __launch_bounds__(256, 4) void k_uv(
    const ushort* __restrict__ nf, const ushort* __restrict__ wijT,
    ushort* __restrict__ UV)
{
    int tid = threadIdx.x;
    int wave = tid >> 6, lane = tid & 63;
    int m16 = lane & 15, quad = lane >> 4;
    int bm = blockIdx.x >> 1, bn = blockIdx.x & 1;
    int base = bn * 512 + wave * 128;

    float4v acc[2][8];
#pragma unroll
    for (int mt = 0; mt < 2; mt++)
#pragma unroll
        for (int nt = 0; nt < 8; nt++) acc[mt][nt] = (float4v)(0.f);

#pragma unroll
    for (int k0 = 0; k0 < NODE_F; k0 += 32) {
        int kk = k0 + quad * 8;
        short8 a0 = *(const short8*)(nf + (bm * 32 + m16) * NODE_F + kk);
        short8 a1 = *(const short8*)(nf + (bm * 32 + 16 + m16) * NODE_F + kk);
#pragma unroll
        for (int nt = 0; nt < 8; nt++) {
            int n = base + nt * 16 + m16;
            short8 b = *(const short8*)(wijT + n * NODE_F + kk);
            acc[0][nt] = __builtin_amdgcn_mfma_f32_16x16x32_bf16(a0, b, acc[0][nt], 0, 0, 0);
            acc[1][nt] = __builtin_amdgcn_mfma_f32_16x16x32_bf16(a1, b, acc[1][nt], 0, 0, 0);
        }
    }
#pragma unroll
    for (int nt = 0; nt < 8; nt++) {
        int colg = base + nt * 16 + m16;
#pragma unroll
        for (int mt = 0; mt < 2; mt++)
#pragma unroll
            for (int t = 0; t < 4; t++) {
                int rr = bm * 32 + mt * 16 + quad * 4 + t;
                UV[(size_t)rr * 1024 + colg] = f2bf(acc[mt][nt][t]);
            }
    }
}

// ---------------- fused edge, per-batch tiling, MTILE=64:
// grid = BATCH * PTILES; block handles 64 pairs of one batch b.
__global__ __launch_bounds__(256, 2) void k_edge4(
    const float* __restrict__ Zc, const ushort* __restrict__ UV,
    const ushort* __restrict__ ew2T, const float* __restrict__ ew3,
    const float* __restrict__ eb2, const float* __restrict__ eb3,
    float* __restrict__ out_edges)
{
    __shared__ __align__(16) ushort h1[MTILE][HIDDEN + 8];   // 66,560 B
    __shared__ float part[MTILE][4];
    __shared__ int uo[MTILE], vo[MTILE];

    int blk = blockIdx.x;
    int b   = blk / PTILES;
    int t0  = (blk - b * PTILES) * MTILE;    // first pair index in batch b

    int tid = threadIdx.x;
    if (tid < MTILE) {
        int p = t0 + tid;
        if (p >= NPAIRS) p = NPAIRS - 1;     // tail: duplicate last pair (write masked)
        int i = 0, off = 0;
        while (p - off >= MAX_NODES - 1 - i) { off += MAX_NODES - 1 - i; ++i; }
        int j = i + 1 + (p - off);
        uo[tid] = (b * MAX_NODES + i) * 1024;
        vo[tid] = (b * MAX_NODES + j) * 1024 + 512;
    }

    int wave = tid >> 6, lane = tid & 63;

    // each lane's 8-col slice of Zc[b] (coalesced 2KB wave read), reused for 16 rows
    int c8 = lane * 8;
    float4v zA = *(const float4v*)(Zc + b * HIDDEN + c8);
    float4v zB = *(const float4v*)(Zc + b * HIDDEN + c8 + 4);
    __syncthreads();

    // ---- assemble h1: wave handles rows [wave*16, wave*16+16); lane covers cols [8l,8l+8)
#pragma unroll
    for (int rr = 0; rr < 16; rr++) {
        int r = wave * 16 + rr;
        short8 u8 = *(const short8*)(UV + uo[r] + c8);
        short8 v8 = *(const short8*)(UV + vo[r] + c8);
        short8 hh;
#pragma unroll
        for (int e = 0; e < 8; e++) {
            float zz = (e < 4) ? zA[e] : zB[e - 4];
            hh[e] = (short)f2bf(fmaxf(zz + bf2f((ushort)u8[e]) + bf2f((ushort)v8[e]), 0.f));
        }
        *(short8*)&h1[r][c8] = hh;
    }
    __syncthreads();

    int m16 = lane & 15, quad = lane >> 4;

    // per-lane epilogue constants
    float eb2v[4], ew3v[4];
    const ushort* bbase[4];
#pragma unroll
    for (int nt = 0; nt < 4; nt++) {
        int col = wave * 64 + nt * 16 + m16;
        eb2v[nt] = eb2[col];
        ew3v[nt] = ew3[col];
        bbase[nt] = ew2T + col * HIDDEN;
    }

    // ---- GEMM2: (64 x 512) x (512 x 256); wave covers 64 cols, 4 m-subtiles
    float4v acc2[4][4];
#pragma unroll
    for (int mt = 0; mt < 4; mt++)
#pragma unroll
        for (int nt = 0; nt < 4; nt++) acc2[mt][nt] = (float4v)(0.f);

    int kk0 = quad * 8;
#pragma unroll
    for (int it = 0; it < 16; ++it) {
        int kk = it * 32 + kk0;
        short8 b0 = *(const short8*)(bbase[0] + kk);
        short8 b1 = *(const short8*)(bbase[1] + kk);
        short8 b2 = *(const short8*)(bbase[2] + kk);
        short8 b3 = *(const short8*)(bbase[3] + kk);
        short8 a0 = *(const short8*)&h1[m16][kk];
        short8 a1 = *(const short8*)&h1[16 + m16][kk];
        short8 a2 = *(const short8*)&h1[32 + m16][kk];
        short8 a3 = *(const short8*)&h1[48 + m16][kk];
        acc2[0][0] = __builtin_amdgcn_mfma_f32_16x16x32_bf16(a0, b0, acc2[0][0], 0, 0, 0);
        acc2[1][0] = __builtin_amdgcn_mfma_f32_16x16x32_bf16(a1, b0, acc2[1][0], 0, 0, 0);
        acc2[2][0] = __builtin_amdgcn_mfma_f32_16x16x32_bf16(a2, b0, acc2[2][0], 0, 0, 0);
        acc2[3][0] = __builtin_amdgcn_mfma_f32_16x16x32_bf16(a3, b0, acc2[3][0], 0, 0, 0);
        acc2[0][1] = __builtin_amdgcn_mfma_f32_16x16x32_bf16(a0, b1, acc2[0][1], 0, 0, 0);
        acc2[1][1] = __builtin_amdgcn_mfma_f32_16x16x32_bf16(a1, b1, acc2[1][1], 0, 0, 0);
        acc2[2][1] = __builtin_amdgcn_mfma_f32_16x16x32_bf16(a2, b1, acc2[2][1], 0, 0, 0);
        acc2[3][1] = __builtin_amdgcn_mfma_f32_16x16x32_bf16(a3, b1, acc2[3][1], 0, 0, 0);
        acc2[0][2] = __builtin_amdgcn_mfma_f32_16x16x32_bf16(a0, b2, acc2[0][2], 0, 0, 0);
        acc2[1][2] = __builtin_amdgcn_mfma_f32_16x16x32_bf16(a1, b2, acc2[1][2], 0, 0, 0);
        acc2[2][2] = __builtin_amdgcn_mfma_f32_16x16x32_bf16(a2, b2, acc2[2][2], 0, 0, 0);
        acc2[3][2] = __builtin_amdgcn_mfma_f32_16x16x32_bf16(a3, b2, acc2[3][2], 0, 0, 0);
        acc2[0][3] = __builtin_amdgcn_mfma_f32_16x16x32_bf16(a0, b3, acc2[0][3], 0, 0, 0);
        acc2[1][3] = __builtin_amdgcn_mfma_f32_16x16x32_bf16(a1, b3, acc2[1][3], 0, 0, 0);
        acc2[2][3] = __builtin_amdgcn_mfma_f32_16x16x32_bf16(a2, b3, acc2[2][3], 0, 0, 0);
        acc2[3][3] = __builtin_amdgcn_mfma_f32_16x16x32_bf16(a3, b3, acc2[3][3], 0, 0, 0);
    }

    // ---- fused relu + 256-dot via shfl-reduce over m16 lanes
#pragma unroll
    for (int mt = 0; mt < 4; mt++)
#pragma unroll
        for (int t = 0; t < 4; t++) {
            float s = 0.f;
#pragma unroll
            for (int nt = 0; nt < 4; nt++)
                s += fmaxf(acc2[mt][nt][t] + eb2v[nt], 0.f) * ew3v[nt];
            s += __shfl_xor(s, 1);
            s += __shfl_xor(s, 2);
            s += __shfl_xor(s, 4);
            s += __shfl_xor(s, 8);
            if (m16 == 0) part[mt * 16 + quad * 4 + t][wave] = s;
        }
    __syncthreads();

    if (tid < MTILE && t0 + tid < NPAIRS) {
        float v = part[tid][0] + part[tid][1] + part[tid][2] + part[tid][3] + eb3[0];
        out_edges[b * NPAIRS + t0 + tid] = sigmoidf(v);
    }
}

extern "C" void kernel_launch(void* const* d_in, const int* in_sizes, int n_in,
                              void* d_out, int out_size, void* d_ws, size_t ws_size,
                              hipStream_t stream) {
    const float* z   = (const float*)d_in[0];
    const float* nw1 = (const float*)d_in[1];
    const float* nb1 = (const float*)d_in[2];
    const float* nw2 = (const float*)d_in[3];
    const float* nb2 = (const float*)d_in[4];
    const float* nw3 = (const float*)d_in[5];
    const float* nb3 = (const float*)d_in[6];
    const float* ew1 = (const float*)d_in[7];
    const float* eb1 = (const float*)d_in[8];
    const float* ew2 = (const float*)d_in[9];
    const float* eb2 = (const float*)d_in[10];
    const float* ew3 = (const float*)d_in[11];
    const float* eb3 = (const float*)d_in[12];

    char* ws = (char*)d_ws;
    float*  h1f  = (float*)(ws);                     // 128*512*4      = 262144
    ushort* h2b  = (ushort*)(ws + 262144);           // 128*512*2      = 131072
    ushort* nf   = (ushort*)(ws + 393216);           // 128*6400*2     = 1638400
    ushort* ew2T = (ushort*)(ws + 2031616);          // 256*512*2      = 262144
    ushort* wijT = (ushort*)(ws + 2293760);          // 1024*128*2     = 262144
    ushort* nw3T = (ushort*)(ws + 2555904);          // 6400*512*2     = 6553600
    float*  Zc   = (float*)(ws + 9109504);           // 128*512*4      = 262144
    ushort* UV   = (ushort*)(ws + 9371648);          // 6400*1024*2    = 13107200
                                                     // total 22478848 B (~21.4 MB)

    float* out_nodes = (float*)d_out;                // 128*6400
    float* out_edges = out_nodes + BATCH * NODE_OUT; // 128*1225

    k_prep_all<<<PREPK_NB, 256, 0, stream>>>(nw3, nw3T, ew1, ew2, ew2T, wijT,
                                             z, eb1, Zc, nw1, nb1, h1f);
    k_node_h2<<<256, 256, 0, stream>>>(h1f, nw2, nb2, h2b);
    k_node_out_mfma<<<400, 256, 0, stream>>>(h2b, nw3T, nb3, out_nodes, nf);
    k_uv<<<400, 256, 0, stream>>>(nf, wijT, UV);
    k_edge4<<<BATCH * PTILES, 256, 0, stream>>>(Zc, UV, ew2T, ew3,
                                                eb2, eb3, out_edges);
}

// Round 8
// 248.813 us; speedup vs baseline: 2.7497x; 1.0452x over previous
//
#include <hip/hip_runtime.h>
#include <math.h>

#define LATENT 256
#define HIDDEN 512
#define NODE_F 128
#define MAX_NODES 50
#define NPAIRS 1225        // 50*49/2
#define BATCH 128
#define NODE_OUT 6400      // MAX_NODES*NODE_F
#define MTILE 64           // edge rows per block
#define PTILES 20          // ceil(1225/64)

typedef __attribute__((ext_vector_type(8))) short short8;
typedef __attribute__((ext_vector_type(4))) float float4v;

__device__ __forceinline__ float bf2f(ushort u) {
    union { unsigned int i; float f; } v; v.i = ((unsigned int)u) << 16; return v.f;
}
__device__ __forceinline__ ushort f2bf(float f) {
    union { unsigned int i; float f; } v; v.f = f;
    unsigned int r = v.i + 0x7fffu + ((v.i >> 16) & 1u);   // RNE
    return (ushort)(r >> 16);
}
__device__ __forceinline__ float sigmoidf(float x) {
    return 1.0f / (1.0f + __expf(-x));
}

// ================= fused prep kernel: 4 independent jobs, one launch =================
#define TR3_B0   0
#define PREP_B0  800
#define ZC_B0    1824
#define H1_B0    2080
#define PREPK_NB 2336

__global__ __launch_bounds__(256) void k_prep_all(
    const float* __restrict__ nw3, ushort* __restrict__ nw3T,
    const float* __restrict__ ew1, const float* __restrict__ ew2,
    ushort* __restrict__ ew2T, ushort* __restrict__ wijT,
    const float* __restrict__ z, const float* __restrict__ eb1,
    float* __restrict__ Zc,
    const float* __restrict__ nw1, const float* __restrict__ nb1,
    float* __restrict__ h1f)
{
    __shared__ float smem[64 * 65];
    int b = blockIdx.x;
    int tid = threadIdx.x;

    if (b < PREP_B0) {
        // ---- nw3 transpose, 64x64 tiles (8 k-tiles x 100 n-tiles)
        int bb = b - TR3_B0;
        int k0 = (bb & 7) * 64;
        int n0 = (bb >> 3) * 64;
        int tx = tid & 63, ty = tid >> 6;   // 64 x 4
#pragma unroll
        for (int r = 0; r < 16; r++) {
            int row = r * 4 + ty;
            smem[row * 65 + tx] = nw3[(k0 + row) * NODE_OUT + n0 + tx];
        }
        __syncthreads();
#pragma unroll
        for (int c = 0; c < 16; c++) {
            int n = c * 4 + ty;
            nw3T[(size_t)(n0 + n) * HIDDEN + k0 + tx] = f2bf(smem[tx * 65 + n]);
        }
    } else if (b < ZC_B0) {
        int t = (b - PREP_B0) * 256 + tid;
        if (t < 256 * 512) {
            int n = t >> 9, k = t & 511;
            ew2T[t] = f2bf(ew2[k * 256 + n]);
        } else {
            int u = t - 256 * 512;          // < 1024*128
            int n = u >> 7, k = u & 127;
            float s = (n < 512) ? ew1[(256 + k) * 512 + n] : ew1[(384 + k) * 512 + (n - 512)];
            wijT[u] = f2bf(s);
        }
    } else if (b < H1_B0) {
        // ---- Zc = z @ W_z + eb1
        int b2 = b - ZC_B0;
        int r = b2 >> 1, o = (b2 & 1) * 256 + tid;
        float* zs = smem;
        zs[tid] = z[r * LATENT + tid];
        __syncthreads();
        float acc = 0.f;
#pragma unroll 8
        for (int k = 0; k < LATENT; k++) acc += zs[k] * ew1[k * HIDDEN + o];
        Zc[r * HIDDEN + o] = acc + eb1[o];
    } else {
        // ---- node h1
        int b2 = b - H1_B0;
        int r = b2 >> 1, o = (b2 & 1) * 256 + tid;
        float* zs = smem;
        zs[tid] = z[r * LATENT + tid];
        __syncthreads();
        float acc = 0.f;
#pragma unroll 8
        for (int k = 0; k < LATENT; k++) acc += zs[k] * nw1[k * HIDDEN + o];
        acc += nb1[o];
        h1f[r * HIDDEN + o] = fmaxf(acc, 0.f);
    }
}

// ---------------- node MLP layer 2: h2b = bf16(relu(h1 @ nw2 + nb2)), 256 blocks
__global__ __launch_bounds__(256) void k_node_h2(
    const float* __restrict__ h1, const float* __restrict__ nw2,
    const float* __restrict__ nb2, ushort* __restrict__ h2b)
{
    __shared__ float hs[HIDDEN];
    int r = blockIdx.x >> 1;
    int o = (blockIdx.x & 1) * 256 + threadIdx.x;
    hs[threadIdx.x] = h1[r * HIDDEN + threadIdx.x];
    hs[threadIdx.x + 256] = h1[r * HIDDEN + threadIdx.x + 256];
    __syncthreads();
    float acc = 0.f;
#pragma unroll 8
    for (int k = 0; k < HIDDEN; k++) acc += hs[k] * nw2[k * HIDDEN + o];
    acc += nb2[o];
    h2b[r * HIDDEN + o] = f2bf(fmaxf(acc, 0.f));
}

// ---------------- node layer 3 via MFMA: grid 400 = 100 n-tiles(64) x 4 m-tiles(32)
__global__ __launch_bounds__(256, 4) void k_node_out_mfma(
    const ushort* __restrict__ h2b, const ushort* __restrict__ nw3T,
    const float* __restrict__ nb3, float* __restrict__ node_probs,
    ushort* __restrict__ node_feats)
{
    int tid = threadIdx.x;
    int wave = tid >> 6, lane = tid & 63;
    int m16 = lane & 15, quad = lane >> 4;
    int n0 = (blockIdx.x >> 2) * 64;
    int m0 = (blockIdx.x & 3) * 32;
    int col = n0 + wave * 16 + m16;

    float4v acc[2];
    acc[0] = (float4v)(0.f); acc[1] = (float4v)(0.f);

    const ushort* bb = nw3T + (size_t)col * HIDDEN;
    const ushort* a0p = h2b + (m0 + m16) * HIDDEN;
    const ushort* a1p = h2b + (m0 + 16 + m16) * HIDDEN;
#pragma unroll
    for (int it = 0; it < 16; ++it) {
        int kk = it * 32 + quad * 8;
        short8 b = *(const short8*)(bb + kk);
        short8 a0 = *(const short8*)(a0p + kk);
        short8 a1 = *(const short8*)(a1p + kk);
        acc[0] = __builtin_amdgcn_mfma_f32_16x16x32_bf16(a0, b, acc[0], 0, 0, 0);
        acc[1] = __builtin_amdgcn_mfma_f32_16x16x32_bf16(a1, b, acc[1], 0, 0, 0);
    }
    float bias = nb3[col];
#pragma unroll
    for (int mt = 0; mt < 2; mt++)
#pragma unroll
        for (int t = 0; t < 4; t++) {
            int row = m0 + mt * 16 + quad * 4 + t;
            float v = acc[mt][t] + bias;
            node_probs[(size_t)row * NODE_OUT + col] = sigmoidf(v);
            node_feats[(size_t)row * NODE_OUT + col] = f2bf(v);
        }
}

// ---------------- UV = node_feats @ [W_i|W_j]   (6400 x 1024, bf16 out)
// grid 400 = 100 m-tiles(64 rows) x 4 n-quarters(256 cols); wave = 64 cols, mt=4
__global__ __launch_bounds__(256, 4) void k_uv(
    const ushort* __restrict__ nf, const ushort* __restrict__ wijT,
    ushort* __restrict__ UV)
{
    int tid = threadIdx.x;
    int wave = tid >> 6, lane = tid & 63;
    int m16 = lane & 15, quad = lane >> 4;
    int bm = blockIdx.x >> 2, bn = blockIdx.x & 3;
    int base = bn * 256 + wave * 64;
    int r0 = bm * 64;

    float4v acc[4][4];
#pragma unroll
    for (int mt = 0; mt < 4; mt++)
#pragma unroll
        for (int nt = 0; nt < 4; nt++) acc[mt][nt] = (float4v)(0.f);

#pragma unroll
    for (int k0 = 0; k0 < NODE_F; k0 += 32) {
        int kk = k0 + quad * 8;
        short8 a0 = *(const short8*)(nf + (r0 + m16) * NODE_F + kk);
        short8 a1 = *(const short8*)(nf + (r0 + 16 + m16) * NODE_F + kk);
        short8 a2 = *(const short8*)(nf + (r0 + 32 + m16) * NODE_F + kk);
        short8 a3 = *(const short8*)(nf + (r0 + 48 + m16) * NODE_F + kk);
#pragma unroll
        for (int nt = 0; nt < 4; nt++) {
            int n = base + nt * 16 + m16;
            short8 b = *(const short8*)(wijT + n * NODE_F + kk);
            acc[0][nt] = __builtin_amdgcn_mfma_f32_16x16x32_bf16(a0, b, acc[0][nt], 0, 0, 0);
            acc[1][nt] = __builtin_amdgcn_mfma_f32_16x16x32_bf16(a1, b, acc[1][nt], 0, 0, 0);
            acc[2][nt] = __builtin_amdgcn_mfma_f32_16x16x32_bf16(a2, b, acc[2][nt], 0, 0, 0);
            acc[3][nt] = __builtin_amdgcn_mfma_f32_16x16x32_bf16(a3, b, acc[3][nt], 0, 0, 0);
        }
    }
#pragma unroll
    for (int nt = 0; nt < 4; nt++) {
        int colg = base + nt * 16 + m16;
#pragma unroll
        for (int mt = 0; mt < 4; mt++)
#pragma unroll
            for (int t = 0; t < 4; t++) {
                int rr = r0 + mt * 16 + quad * 4 + t;
                UV[(size_t)rr * 1024 + colg] = f2bf(acc[mt][nt][t]);
            }
    }
}

// ---------------- fused edge, per-batch tiling, MTILE=64, 512 threads / 8 waves:
// grid = BATCH * PTILES; block handles 64 pairs of one batch b; wave covers 32 N-cols.
__global__ __launch_bounds__(512, 4) void k_edge5(
    const float* __restrict__ Zc, const ushort* __restrict__ UV,
    const ushort* __restrict__ ew2T, const float* __restrict__ ew3,
    const float* __restrict__ eb2, const float* __restrict__ eb3,
    float* __restrict__ out_edges)
{
    __shared__ __align__(16) ushort h1[MTILE][HIDDEN + 8];   // 66,560 B
    __shared__ float part[MTILE][8];                         // 2,048 B
    __shared__ int uo[MTILE], vo[MTILE];

    int blk = blockIdx.x;
    int b   = blk / PTILES;
    int t0  = (blk - b * PTILES) * MTILE;    // first pair index in batch b

    int tid = threadIdx.x;
    if (tid < MTILE) {
        int p = t0 + tid;
        if (p >= NPAIRS) p = NPAIRS - 1;     // tail: duplicate last pair (write masked)
        int i = 0, off = 0;
        while (p - off >= MAX_NODES - 1 - i) { off += MAX_NODES - 1 - i; ++i; }
        int j = i + 1 + (p - off);
        uo[tid] = (b * MAX_NODES + i) * 1024;
        vo[tid] = (b * MAX_NODES + j) * 1024 + 512;
    }

    int wave = tid >> 6, lane = tid & 63;

    // each lane's 8-col slice of Zc[b] (coalesced 2KB wave read), reused for 8 rows
    int c8 = lane * 8;
    float4v zA = *(const float4v*)(Zc + b * HIDDEN + c8);
    float4v zB = *(const float4v*)(Zc + b * HIDDEN + c8 + 4);
    __syncthreads();

    // ---- assemble h1: wave handles rows [wave*8, wave*8+8); lane covers cols [8l,8l+8)
#pragma unroll
    for (int rr = 0; rr < 8; rr++) {
        int r = wave * 8 + rr;
        short8 u8 = *(const short8*)(UV + uo[r] + c8);
        short8 v8 = *(const short8*)(UV + vo[r] + c8);
        short8 hh;
#pragma unroll
        for (int e = 0; e < 8; e++) {
            float zz = (e < 4) ? zA[e] : zB[e - 4];
            hh[e] = (short)f2bf(fmaxf(zz + bf2f((ushort)u8[e]) + bf2f((ushort)v8[e]), 0.f));
        }
        *(short8*)&h1[r][c8] = hh;
    }
    __syncthreads();

    int m16 = lane & 15, quad = lane >> 4;

    // per-lane epilogue constants (wave covers cols [wave*32, wave*32+32))
    float eb2v[2], ew3v[2];
    const ushort* bbase[2];
#pragma unroll
    for (int nt = 0; nt < 2; nt++) {
        int col = wave * 32 + nt * 16 + m16;
        eb2v[nt] = eb2[col];
        ew3v[nt] = ew3[col];
        bbase[nt] = ew2T + col * HIDDEN;
    }

    // ---- GEMM2: (64 x 512) x (512 x 256); wave covers 32 cols, 4 m-subtiles
    float4v acc2[4][2];
#pragma unroll
    for (int mt = 0; mt < 4; mt++)
#pragma unroll
        for (int nt = 0; nt < 2; nt++) acc2[mt][nt] = (float4v)(0.f);

    int kk0 = quad * 8;
#pragma unroll
    for (int it = 0; it < 16; ++it) {
        int kk = it * 32 + kk0;
        short8 b0 = *(const short8*)(bbase[0] + kk);
        short8 b1 = *(const short8*)(bbase[1] + kk);
        short8 a0 = *(const short8*)&h1[m16][kk];
        short8 a1 = *(const short8*)&h1[16 + m16][kk];
        short8 a2 = *(const short8*)&h1[32 + m16][kk];
        short8 a3 = *(const short8*)&h1[48 + m16][kk];
        acc2[0][0] = __builtin_amdgcn_mfma_f32_16x16x32_bf16(a0, b0, acc2[0][0], 0, 0, 0);
        acc2[1][0] = __builtin_amdgcn_mfma_f32_16x16x32_bf16(a1, b0, acc2[1][0], 0, 0, 0);
        acc2[2][0] = __builtin_amdgcn_mfma_f32_16x16x32_bf16(a2, b0, acc2[2][0], 0, 0, 0);
        acc2[3][0] = __builtin_amdgcn_mfma_f32_16x16x32_bf16(a3, b0, acc2[3][0], 0, 0, 0);
        acc2[0][1] = __builtin_amdgcn_mfma_f32_16x16x32_bf16(a0, b1, acc2[0][1], 0, 0, 0);
        acc2[1][1] = __builtin_amdgcn_mfma_f32_16x16x32_bf16(a1, b1, acc2[1][1], 0, 0, 0);
        acc2[2][1] = __builtin_amdgcn_mfma_f32_16x16x32_bf16(a2, b1, acc2[2][1], 0, 0, 0);
        acc2[3][1] = __builtin_amdgcn_mfma_f32_16x16x32_bf16(a3, b1, acc2[3][1], 0, 0, 0);
    }

    // ---- fused relu + partial dot (32 cols) via shfl-reduce over m16 lanes
#pragma unroll
    for (int mt = 0; mt < 4; mt++)
#pragma unroll
        for (int t = 0; t < 4; t++) {
            float s = 0.f;
#pragma unroll
            for (int nt = 0; nt < 2; nt++)
                s += fmaxf(acc2[mt][nt][t] + eb2v[nt], 0.f) * ew3v[nt];
            s += __shfl_xor(s, 1);
            s += __shfl_xor(s, 2);
            s += __shfl_xor(s, 4);
            s += __shfl_xor(s, 8);
            if (m16 == 0) part[mt * 16 + quad * 4 + t][wave] = s;
        }
    __syncthreads();

    if (tid < MTILE && t0 + tid < NPAIRS) {
        float v = eb3[0];
#pragma unroll
        for (int w = 0; w < 8; w++) v += part[tid][w];
        out_edges[b * NPAIRS + t0 + tid] = sigmoidf(v);
    }
}

extern "C" void kernel_launch(void* const* d_in, const int* in_sizes, int n_in,
                              void* d_out, int out_size, void* d_ws, size_t ws_size,
                              hipStream_t stream) {
    const float* z   = (const float*)d_in[0];
    const float* nw1 = (const float*)d_in[1];
    const float* nb1 = (const float*)d_in[2];
    const float* nw2 = (const float*)d_in[3];
    const float* nb2 = (const float*)d_in[4];
    const float* nw3 = (const float*)d_in[5];
    const float* nb3 = (const float*)d_in[6];
    const float* ew1 = (const float*)d_in[7];
    const float* eb1 = (const float*)d_in[8];
    const float* ew2 = (const float*)d_in[9];
    const float* eb2 = (const float*)d_in[10];
    const float* ew3 = (const float*)d_in[11];
    const float* eb3 = (const float*)d_in[12];

    char* ws = (char*)d_ws;
    float*  h1f  = (float*)(ws);                     // 128*512*4      = 262144
    ushort* h2b  = (ushort*)(ws + 262144);           // 128*512*2      = 131072
    ushort* nf   = (ushort*)(ws + 393216);           // 128*6400*2     = 1638400
    ushort* ew2T = (ushort*)(ws + 2031616);          // 256*512*2      = 262144
    ushort* wijT = (ushort*)(ws + 2293760);          // 1024*128*2     = 262144
    ushort* nw3T = (ushort*)(ws + 2555904);          // 6400*512*2     = 6553600
    float*  Zc   = (float*)(ws + 9109504);           // 128*512*4      = 262144
    ushort* UV   = (ushort*)(ws + 9371648);          // 6400*1024*2    = 13107200
                                                     // total 22478848 B (~21.4 MB)

    float* out_nodes = (float*)d_out;                // 128*6400
    float* out_edges = out_nodes + BATCH * NODE_OUT; // 128*1225

    k_prep_all<<<PREPK_NB, 256, 0, stream>>>(nw3, nw3T, ew1, ew2, ew2T, wijT,
                                             z, eb1, Zc, nw1, nb1, h1f);
    k_node_h2<<<256, 256, 0, stream>>>(h1f, nw2, nb2, h2b);
    k_node_out_mfma<<<400, 256, 0, stream>>>(h2b, nw3T, nb3, out_nodes, nf);
    k_uv<<<400, 256, 0, stream>>>(nf, wijT, UV);
    k_edge5<<<BATCH * PTILES, 512, 0, stream>>>(Zc, UV, ew2T, ew3,
                                                eb2, eb3, out_edges);
}

// Round 9
// 243.379 us; speedup vs baseline: 2.8111x; 1.0223x over previous
//
#include <hip/hip_runtime.h>
#include <math.h>

#define LATENT 256
#define HIDDEN 512
#define NODE_F 128
#define MAX_NODES 50
#define NPAIRS 1225        // 50*49/2
#define BATCH 128
#define NODE_OUT 6400      // MAX_NODES*NODE_F
#define MTILE 64           // edge rows per block
#define PTILES 20          // ceil(1225/64)

typedef __attribute__((ext_vector_type(8))) short short8;
typedef __attribute__((ext_vector_type(4))) float float4v;

__device__ __forceinline__ float bf2f(ushort u) {
    union { unsigned int i; float f; } v; v.i = ((unsigned int)u) << 16; return v.f;
}
__device__ __forceinline__ ushort f2bf(float f) {
    union { unsigned int i; float f; } v; v.f = f;
    unsigned int r = v.i + 0x7fffu + ((v.i >> 16) & 1u);   // RNE
    return (ushort)(r >> 16);
}
__device__ __forceinline__ float sigmoidf(float x) {
    return 1.0f / (1.0f + __expf(-x));
}

// ================= fused prep kernel: 5 independent jobs, one launch =================
// [0,800)      nw3T transpose
// [800,1824)   ew2T / wijT transposes
// [1824,2080)  Zc = z @ W_z + eb1
// [2080,2336)  fused node MLP L1+L2: h2b = bf16(relu(relu(z@nw1+nb1)@nw2+nb2))
// [2336,2341)  pair-decode table ptab[p] = (i<<8)|j
#define TR3_B0   0
#define PREP_B0  800
#define ZC_B0    1824
#define ND_B0    2080
#define PT_B0    2336
#define PREPK_NB 2341

__global__ __launch_bounds__(256) void k_prep_all(
    const float* __restrict__ nw3, ushort* __restrict__ nw3T,
    const float* __restrict__ ew1, const float* __restrict__ ew2,
    ushort* __restrict__ ew2T, ushort* __restrict__ wijT,
    const float* __restrict__ z, const float* __restrict__ eb1,
    float* __restrict__ Zc,
    const float* __restrict__ nw1, const float* __restrict__ nb1,
    const float* __restrict__ nw2, const float* __restrict__ nb2,
    ushort* __restrict__ h2b, int* __restrict__ ptab)
{
    __shared__ float smem[64 * 65];
    int b = blockIdx.x;
    int tid = threadIdx.x;

    if (b < PREP_B0) {
        // ---- nw3 transpose, 64x64 tiles (8 k-tiles x 100 n-tiles)
        int bb = b - TR3_B0;
        int k0 = (bb & 7) * 64;
        int n0 = (bb >> 3) * 64;
        int tx = tid & 63, ty = tid >> 6;   // 64 x 4
#pragma unroll
        for (int r = 0; r < 16; r++) {
            int row = r * 4 + ty;
            smem[row * 65 + tx] = nw3[(k0 + row) * NODE_OUT + n0 + tx];
        }
        __syncthreads();
#pragma unroll
        for (int c = 0; c < 16; c++) {
            int n = c * 4 + ty;
            nw3T[(size_t)(n0 + n) * HIDDEN + k0 + tx] = f2bf(smem[tx * 65 + n]);
        }
    } else if (b < ZC_B0) {
        int t = (b - PREP_B0) * 256 + tid;
        if (t < 256 * 512) {
            int n = t >> 9, k = t & 511;
            ew2T[t] = f2bf(ew2[k * 256 + n]);
        } else {
            int u = t - 256 * 512;          // < 1024*128
            int n = u >> 7, k = u & 127;
            float s = (n < 512) ? ew1[(256 + k) * 512 + n] : ew1[(384 + k) * 512 + (n - 512)];
            wijT[u] = f2bf(s);
        }
    } else if (b < ND_B0) {
        // ---- Zc = z @ W_z + eb1
        int b2 = b - ZC_B0;
        int r = b2 >> 1, o = (b2 & 1) * 256 + tid;
        float* zs = smem;
        zs[tid] = z[r * LATENT + tid];
        __syncthreads();
        float acc = 0.f;
#pragma unroll 8
        for (int k = 0; k < LATENT; k++) acc += zs[k] * ew1[k * HIDDEN + o];
        Zc[r * HIDDEN + o] = acc + eb1[o];
    } else if (b < PT_B0) {
        // ---- fused node MLP: one z-row per block-pair; h1 in LDS, h2b out
        int b2 = b - ND_B0;
        int r = b2 >> 1, half = b2 & 1;
        float* zs = smem;            // 256 floats
        float* hs = smem + 256;      // 512 floats
        zs[tid] = z[r * LATENT + tid];
        __syncthreads();
        float a0 = 0.f, a1 = 0.f;
#pragma unroll 8
        for (int k = 0; k < LATENT; k++) {
            float zk = zs[k];
            a0 += zk * nw1[k * HIDDEN + tid];
            a1 += zk * nw1[k * HIDDEN + tid + 256];
        }
        hs[tid]       = fmaxf(a0 + nb1[tid], 0.f);
        hs[tid + 256] = fmaxf(a1 + nb1[tid + 256], 0.f);
        __syncthreads();
        int o = half * 256 + tid;
        float acc = 0.f;
#pragma unroll 8
        for (int k = 0; k < HIDDEN; k++) acc += hs[k] * nw2[k * HIDDEN + o];
        acc += nb2[o];
        h2b[r * HIDDEN + o] = f2bf(fmaxf(acc, 0.f));
    } else {
        // ---- pair table
        int p = (b - PT_B0) * 256 + tid;
        if (p < NPAIRS) {
            int i = 0, off = 0;
            while (p - off >= MAX_NODES - 1 - i) { off += MAX_NODES - 1 - i; ++i; }
            int j = i + 1 + (p - off);
            ptab[p] = (i << 8) | j;
        }
    }
}

// ---------------- node layer 3 via MFMA: grid 400 = 100 n-tiles(64) x 4 m-tiles(32)
__global__ __launch_bounds__(256, 4) void k_node_out_mfma(
    const ushort* __restrict__ h2b, const ushort* __restrict__ nw3T,
    const float* __restrict__ nb3, float* __restrict__ node_probs,
    ushort* __restrict__ node_feats)
{
    int tid = threadIdx.x;
    int wave = tid >> 6, lane = tid & 63;
    int m16 = lane & 15, quad = lane >> 4;
    int n0 = (blockIdx.x >> 2) * 64;
    int m0 = (blockIdx.x & 3) * 32;
    int col = n0 + wave * 16 + m16;

    float4v acc[2];
    acc[0] = (float4v)(0.f); acc[1] = (float4v)(0.f);

    const ushort* bb = nw3T + (size_t)col * HIDDEN;
    const ushort* a0p = h2b + (m0 + m16) * HIDDEN;
    const ushort* a1p = h2b + (m0 + 16 + m16) * HIDDEN;
#pragma unroll
    for (int it = 0; it < 16; ++it) {
        int kk = it * 32 + quad * 8;
        short8 b = *(const short8*)(bb + kk);
        short8 a0 = *(const short8*)(a0p + kk);
        short8 a1 = *(const short8*)(a1p + kk);
        acc[0] = __builtin_amdgcn_mfma_f32_16x16x32_bf16(a0, b, acc[0], 0, 0, 0);
        acc[1] = __builtin_amdgcn_mfma_f32_16x16x32_bf16(a1, b, acc[1], 0, 0, 0);
    }
    float bias = nb3[col];
#pragma unroll
    for (int mt = 0; mt < 2; mt++)
#pragma unroll
        for (int t = 0; t < 4; t++) {
            int row = m0 + mt * 16 + quad * 4 + t;
            float v = acc[mt][t] + bias;
            node_probs[(size_t)row * NODE_OUT + col] = sigmoidf(v);
            node_feats[(size_t)row * NODE_OUT + col] = f2bf(v);
        }
}

// ---------------- UV = node_feats @ [W_i|W_j]   (6400 x 1024, bf16 out)
// grid 400 = 100 m-tiles(64 rows) x 4 n-quarters(256 cols); wave = 64 cols, mt=4
__global__ __launch_bounds__(256, 4) void k_uv(
    const ushort* __restrict__ nf, const ushort* __restrict__ wijT,
    ushort* __restrict__ UV)
{
    int tid = threadIdx.x;
    int wave = tid >> 6, lane = tid & 63;
    int m16 = lane & 15, quad = lane >> 4;
    int bm = blockIdx.x >> 2, bn = blockIdx.x & 3;
    int base = bn * 256 + wave * 64;
    int r0 = bm * 64;

    float4v acc[4][4];
#pragma unroll
    for (int mt = 0; mt < 4; mt++)
#pragma unroll
        for (int nt = 0; nt < 4; nt++) acc[mt][nt] = (float4v)(0.f);

#pragma unroll
    for (int k0 = 0; k0 < NODE_F; k0 += 32) {
        int kk = k0 + quad * 8;
        short8 a0 = *(const short8*)(nf + (r0 + m16) * NODE_F + kk);
        short8 a1 = *(const short8*)(nf + (r0 + 16 + m16) * NODE_F + kk);
        short8 a2 = *(const short8*)(nf + (r0 + 32 + m16) * NODE_F + kk);
        short8 a3 = *(const short8*)(nf + (r0 + 48 + m16) * NODE_F + kk);
#pragma unroll
        for (int nt = 0; nt < 4; nt++) {
            int n = base + nt * 16 + m16;
            short8 b = *(const short8*)(wijT + n * NODE_F + kk);
            acc[0][nt] = __builtin_amdgcn_mfma_f32_16x16x32_bf16(a0, b, acc[0][nt], 0, 0, 0);
            acc[1][nt] = __builtin_amdgcn_mfma_f32_16x16x32_bf16(a1, b, acc[1][nt], 0, 0, 0);
            acc[2][nt] = __builtin_amdgcn_mfma_f32_16x16x32_bf16(a2, b, acc[2][nt], 0, 0, 0);
            acc[3][nt] = __builtin_amdgcn_mfma_f32_16x16x32_bf16(a3, b, acc[3][nt], 0, 0, 0);
        }
    }
#pragma unroll
    for (int nt = 0; nt < 4; nt++) {
        int colg = base + nt * 16 + m16;
#pragma unroll
        for (int mt = 0; mt < 4; mt++)
#pragma unroll
            for (int t = 0; t < 4; t++) {
                int rr = r0 + mt * 16 + quad * 4 + t;
                UV[(size_t)rr * 1024 + colg] = f2bf(acc[mt][nt][t]);
            }
    }
}

// ---------------- fused edge, per-batch tiling, MTILE=64, 512 threads / 8 waves.
// Batched assembly loads + 2-group ping-pong B prefetch.
__global__ __launch_bounds__(512, 4) void k_edge6(
    const float* __restrict__ Zc, const ushort* __restrict__ UV,
    const ushort* __restrict__ ew2T, const float* __restrict__ ew3,
    const float* __restrict__ eb2, const float* __restrict__ eb3,
    const int* __restrict__ ptab, float* __restrict__ out_edges)
{
    __shared__ __align__(16) ushort h1[MTILE][HIDDEN + 8];   // 66,560 B
    __shared__ float part[MTILE][8];
    __shared__ int uo[MTILE], vo[MTILE];

    int blk = blockIdx.x;
    int b   = blk / PTILES;
    int t0  = (blk - b * PTILES) * MTILE;

    int tid = threadIdx.x;
    if (tid < MTILE) {
        int p = t0 + tid;
        if (p >= NPAIRS) p = NPAIRS - 1;     // tail: duplicate last pair (write masked)
        int ij = ptab[p];
        uo[tid] = (b * MAX_NODES + (ij >> 8)) * 1024;
        vo[tid] = (b * MAX_NODES + (ij & 255)) * 1024 + 512;
    }

    int wave = tid >> 6, lane = tid & 63;
    int c8 = lane * 8;
    float4v zA = *(const float4v*)(Zc + b * HIDDEN + c8);
    float4v zB = *(const float4v*)(Zc + b * HIDDEN + c8 + 4);
    __syncthreads();

    // ---- assembly: batch ALL 16 loads first (forces them in flight together)
    short8 uu[8], vv[8];
#pragma unroll
    for (int rr = 0; rr < 8; rr++) {
        int r = wave * 8 + rr;
        uu[rr] = *(const short8*)(UV + uo[r] + c8);
        vv[rr] = *(const short8*)(UV + vo[r] + c8);
    }
#pragma unroll
    for (int rr = 0; rr < 8; rr++) {
        int r = wave * 8 + rr;
        short8 hh;
#pragma unroll
        for (int e = 0; e < 8; e++) {
            float zz = (e < 4) ? zA[e] : zB[e - 4];
            hh[e] = (short)f2bf(fmaxf(zz + bf2f((ushort)uu[rr][e]) + bf2f((ushort)vv[rr][e]), 0.f));
        }
        *(short8*)&h1[r][c8] = hh;
    }
    __syncthreads();

    int m16 = lane & 15, quad = lane >> 4;

    float eb2v[2], ew3v[2];
    const ushort* bbase[2];
#pragma unroll
    for (int nt = 0; nt < 2; nt++) {
        int col = wave * 32 + nt * 16 + m16;
        eb2v[nt] = eb2[col];
        ew3v[nt] = ew3[col];
        bbase[nt] = ew2T + col * HIDDEN;
    }

    // ---- GEMM2: (64 x 512) x (512 x 256); wave covers 32 cols; ping-pong B prefetch
    float4v acc2[4][2];
#pragma unroll
    for (int mt = 0; mt < 4; mt++)
#pragma unroll
        for (int nt = 0; nt < 2; nt++) acc2[mt][nt] = (float4v)(0.f);

    int kk0 = quad * 8;
    short8 bp[2][2][2];  // [stage][iter-in-group][col]
#pragma unroll
    for (int i = 0; i < 2; i++) {
        bp[0][i][0] = *(const short8*)(bbase[0] + i * 32 + kk0);
        bp[0][i][1] = *(const short8*)(bbase[1] + i * 32 + kk0);
    }
#pragma unroll
    for (int g = 0; g < 8; g++) {
        int cur = g & 1, nxt = cur ^ 1;
        if (g < 7) {
#pragma unroll
            for (int i = 0; i < 2; i++) {
                int kk = (g + 1) * 64 + i * 32 + kk0;
                bp[nxt][i][0] = *(const short8*)(bbase[0] + kk);
                bp[nxt][i][1] = *(const short8*)(bbase[1] + kk);
            }
        }
#pragma unroll
        for (int i = 0; i < 2; i++) {
            int kk = g * 64 + i * 32 + kk0;
            short8 a0 = *(const short8*)&h1[m16][kk];
            short8 a1 = *(const short8*)&h1[16 + m16][kk];
            short8 a2 = *(const short8*)&h1[32 + m16][kk];
            short8 a3 = *(const short8*)&h1[48 + m16][kk];
            acc2[0][0] = __builtin_amdgcn_mfma_f32_16x16x32_bf16(a0, bp[cur][i][0], acc2[0][0], 0, 0, 0);
            acc2[1][0] = __builtin_amdgcn_mfma_f32_16x16x32_bf16(a1, bp[cur][i][0], acc2[1][0], 0, 0, 0);
            acc2[2][0] = __builtin_amdgcn_mfma_f32_16x16x32_bf16(a2, bp[cur][i][0], acc2[2][0], 0, 0, 0);
            acc2[3][0] = __builtin_amdgcn_mfma_f32_16x16x32_bf16(a3, bp[cur][i][0], acc2[3][0], 0, 0, 0);
            acc2[0][1] = __builtin_amdgcn_mfma_f32_16x16x32_bf16(a0, bp[cur][i][1], acc2[0][1], 0, 0, 0);
            acc2[1][1] = __builtin_amdgcn_mfma_f32_16x16x32_bf16(a1, bp[cur][i][1], acc2[1][1], 0, 0, 0);
            acc2[2][1] = __builtin_amdgcn_mfma_f32_16x16x32_bf16(a2, bp[cur][i][1], acc2[2][1], 0, 0, 0);
            acc2[3][1] = __builtin_amdgcn_mfma_f32_16x16x32_bf16(a3, bp[cur][i][1], acc2[3][1], 0, 0, 0);
        }
    }

    // ---- fused relu + partial dot (32 cols) via shfl-reduce over m16 lanes
#pragma unroll
    for (int mt = 0; mt < 4; mt++)
#pragma unroll
        for (int t = 0; t < 4; t++) {
            float s = 0.f;
#pragma unroll
            for (int nt = 0; nt < 2; nt++)
                s += fmaxf(acc2[mt][nt][t] + eb2v[nt], 0.f) * ew3v[nt];
            s += __shfl_xor(s, 1);
            s += __shfl_xor(s, 2);
            s += __shfl_xor(s, 4);
            s += __shfl_xor(s, 8);
            if (m16 == 0) part[mt * 16 + quad * 4 + t][wave] = s;
        }
    __syncthreads();

    if (tid < MTILE && t0 + tid < NPAIRS) {
        float v = eb3[0];
#pragma unroll
        for (int w = 0; w < 8; w++) v += part[tid][w];
        out_edges[b * NPAIRS + t0 + tid] = sigmoidf(v);
    }
}

extern "C" void kernel_launch(void* const* d_in, const int* in_sizes, int n_in,
                              void* d_out, int out_size, void* d_ws, size_t ws_size,
                              hipStream_t stream) {
    const float* z   = (const float*)d_in[0];
    const float* nw1 = (const float*)d_in[1];
    const float* nb1 = (const float*)d_in[2];
    const float* nw2 = (const float*)d_in[3];
    const float* nb2 = (const float*)d_in[4];
    const float* nw3 = (const float*)d_in[5];
    const float* nb3 = (const float*)d_in[6];
    const float* ew1 = (const float*)d_in[7];
    const float* eb1 = (const float*)d_in[8];
    const float* ew2 = (const float*)d_in[9];
    const float* eb2 = (const float*)d_in[10];
    const float* ew3 = (const float*)d_in[11];
    const float* eb3 = (const float*)d_in[12];

    char* ws = (char*)d_ws;
    int*    ptab = (int*)(ws);                       // 1225*4 (in old h1f slot)
    ushort* h2b  = (ushort*)(ws + 262144);           // 128*512*2      = 131072
    ushort* nf   = (ushort*)(ws + 393216);           // 128*6400*2     = 1638400
    ushort* ew2T = (ushort*)(ws + 2031616);          // 256*512*2      = 262144
    ushort* wijT = (ushort*)(ws + 2293760);          // 1024*128*2     = 262144
    ushort* nw3T = (ushort*)(ws + 2555904);          // 6400*512*2     = 6553600
    float*  Zc   = (float*)(ws + 9109504);           // 128*512*4      = 262144
    ushort* UV   = (ushort*)(ws + 9371648);          // 6400*1024*2    = 13107200
                                                     // total 22478848 B (~21.4 MB)

    float* out_nodes = (float*)d_out;                // 128*6400
    float* out_edges = out_nodes + BATCH * NODE_OUT; // 128*1225

    k_prep_all<<<PREPK_NB, 256, 0, stream>>>(nw3, nw3T, ew1, ew2, ew2T, wijT,
                                             z, eb1, Zc, nw1, nb1, nw2, nb2,
                                             h2b, ptab);
    k_node_out_mfma<<<400, 256, 0, stream>>>(h2b, nw3T, nb3, out_nodes, nf);
    k_uv<<<400, 256, 0, stream>>>(nf, wijT, UV);
    k_edge6<<<BATCH * PTILES, 512, 0, stream>>>(Zc, UV, ew2T, ew3,
                                                eb2, eb3, ptab, out_edges);
}

// Round 10
// 232.426 us; speedup vs baseline: 2.9436x; 1.0471x over previous
//
#include <hip/hip_runtime.h>
#include <math.h>

#define LATENT 256
#define HIDDEN 512
#define NODE_F 128
#define MAX_NODES 50
#define NPAIRS 1225        // 50*49/2
#define BATCH 128
#define NODE_OUT 6400      // MAX_NODES*NODE_F
#define MTILE 64           // edge rows per tile
#define TPB 5              // tiles per block (20 tiles/batch = 4 blocks/batch)
#define EDGE_BLOCKS 512    // 128 batches * 4

typedef __attribute__((ext_vector_type(8))) short short8;
typedef __attribute__((ext_vector_type(4))) float float4v;

__device__ __forceinline__ float bf2f(ushort u) {
    union { unsigned int i; float f; } v; v.i = ((unsigned int)u) << 16; return v.f;
}
__device__ __forceinline__ ushort f2bf(float f) {
    union { unsigned int i; float f; } v; v.f = f;
    unsigned int r = v.i + 0x7fffu + ((v.i >> 16) & 1u);   // RNE
    return (ushort)(r >> 16);
}
__device__ __forceinline__ float sigmoidf(float x) {
    return 1.0f / (1.0f + __expf(-x));
}

// ================= fused prep kernel: 5 independent jobs, one launch =================
#define TR3_B0   0
#define PREP_B0  800
#define ZC_B0    1824
#define ND_B0    2080
#define PT_B0    2336
#define PREPK_NB 2341

__global__ __launch_bounds__(256) void k_prep_all(
    const float* __restrict__ nw3, ushort* __restrict__ nw3T,
    const float* __restrict__ ew1, const float* __restrict__ ew2,
    ushort* __restrict__ ew2T, ushort* __restrict__ wijT,
    const float* __restrict__ z, const float* __restrict__ eb1,
    float* __restrict__ Zc,
    const float* __restrict__ nw1, const float* __restrict__ nb1,
    const float* __restrict__ nw2, const float* __restrict__ nb2,
    ushort* __restrict__ h2b, int* __restrict__ ptab)
{
    __shared__ float smem[64 * 65];
    int b = blockIdx.x;
    int tid = threadIdx.x;

    if (b < PREP_B0) {
        int bb = b - TR3_B0;
        int k0 = (bb & 7) * 64;
        int n0 = (bb >> 3) * 64;
        int tx = tid & 63, ty = tid >> 6;   // 64 x 4
#pragma unroll
        for (int r = 0; r < 16; r++) {
            int row = r * 4 + ty;
            smem[row * 65 + tx] = nw3[(k0 + row) * NODE_OUT + n0 + tx];
        }
        __syncthreads();
#pragma unroll
        for (int c = 0; c < 16; c++) {
            int n = c * 4 + ty;
            nw3T[(size_t)(n0 + n) * HIDDEN + k0 + tx] = f2bf(smem[tx * 65 + n]);
        }
    } else if (b < ZC_B0) {
        int t = (b - PREP_B0) * 256 + tid;
        if (t < 256 * 512) {
            int n = t >> 9, k = t & 511;
            ew2T[t] = f2bf(ew2[k * 256 + n]);
        } else {
            int u = t - 256 * 512;          // < 1024*128
            int n = u >> 7, k = u & 127;
            float s = (n < 512) ? ew1[(256 + k) * 512 + n] : ew1[(384 + k) * 512 + (n - 512)];
            wijT[u] = f2bf(s);
        }
    } else if (b < ND_B0) {
        // ---- Zc = z @ W_z + eb1
        int b2 = b - ZC_B0;
        int r = b2 >> 1, o = (b2 & 1) * 256 + tid;
        float* zs = smem;
        zs[tid] = z[r * LATENT + tid];
        __syncthreads();
        float acc = 0.f;
#pragma unroll 8
        for (int k = 0; k < LATENT; k++) acc += zs[k] * ew1[k * HIDDEN + o];
        Zc[r * HIDDEN + o] = acc + eb1[o];
    } else if (b < PT_B0) {
        // ---- fused node MLP L1+L2
        int b2 = b - ND_B0;
        int r = b2 >> 1, half = b2 & 1;
        float* zs = smem;            // 256 floats
        float* hs = smem + 256;      // 512 floats
        zs[tid] = z[r * LATENT + tid];
        __syncthreads();
        float a0 = 0.f, a1 = 0.f;
#pragma unroll 8
        for (int k = 0; k < LATENT; k++) {
            float zk = zs[k];
            a0 += zk * nw1[k * HIDDEN + tid];
            a1 += zk * nw1[k * HIDDEN + tid + 256];
        }
        hs[tid]       = fmaxf(a0 + nb1[tid], 0.f);
        hs[tid + 256] = fmaxf(a1 + nb1[tid + 256], 0.f);
        __syncthreads();
        int o = half * 256 + tid;
        float acc = 0.f;
#pragma unroll 8
        for (int k = 0; k < HIDDEN; k++) acc += hs[k] * nw2[k * HIDDEN + o];
        acc += nb2[o];
        h2b[r * HIDDEN + o] = f2bf(fmaxf(acc, 0.f));
    } else {
        int p = (b - PT_B0) * 256 + tid;
        if (p < NPAIRS) {
            int i = 0, off = 0;
            while (p - off >= MAX_NODES - 1 - i) { off += MAX_NODES - 1 - i; ++i; }
            int j = i + 1 + (p - off);
            ptab[p] = (i << 8) | j;
        }
    }
}

// ---------------- node layer 3 via MFMA: grid 400 = 100 n-tiles(64) x 4 m-tiles(32)
__global__ __launch_bounds__(256, 4) void k_node_out_mfma(
    const ushort* __restrict__ h2b, const ushort* __restrict__ nw3T,
    const float* __restrict__ nb3, float* __restrict__ node_probs,
    ushort* __restrict__ node_feats)
{
    int tid = threadIdx.x;
    int wave = tid >> 6, lane = tid & 63;
    int m16 = lane & 15, quad = lane >> 4;
    int n0 = (blockIdx.x >> 2) * 64;
    int m0 = (blockIdx.x & 3) * 32;
    int col = n0 + wave * 16 + m16;

    float4v acc[2];
    acc[0] = (float4v)(0.f); acc[1] = (float4v)(0.f);

    const ushort* bb = nw3T + (size_t)col * HIDDEN;
    const ushort* a0p = h2b + (m0 + m16) * HIDDEN;
    const ushort* a1p = h2b + (m0 + 16 + m16) * HIDDEN;
#pragma unroll
    for (int it = 0; it < 16; ++it) {
        int kk = it * 32 + quad * 8;
        short8 b = *(const short8*)(bb + kk);
        short8 a0 = *(const short8*)(a0p + kk);
        short8 a1 = *(const short8*)(a1p + kk);
        acc[0] = __builtin_amdgcn_mfma_f32_16x16x32_bf16(a0, b, acc[0], 0, 0, 0);
        acc[1] = __builtin_amdgcn_mfma_f32_16x16x32_bf16(a1, b, acc[1], 0, 0, 0);
    }
    float bias = nb3[col];
#pragma unroll
    for (int mt = 0; mt < 2; mt++)
#pragma unroll
        for (int t = 0; t < 4; t++) {
            int row = m0 + mt * 16 + quad * 4 + t;
            float v = acc[mt][t] + bias;
            node_probs[(size_t)row * NODE_OUT + col] = sigmoidf(v);
            node_feats[(size_t)row * NODE_OUT + col] = f2bf(v);
        }
}

// ---------------- UV = node_feats @ [W_i|W_j]   (6400 x 1024, bf16 out)
__global__ __launch_bounds__(256, 4) void k_uv(
    const ushort* __restrict__ nf, const ushort* __restrict__ wijT,
    ushort* __restrict__ UV)
{
    int tid = threadIdx.x;
    int wave = tid >> 6, lane = tid & 63;
    int m16 = lane & 15, quad = lane >> 4;
    int bm = blockIdx.x >> 2, bn = blockIdx.x & 3;
    int base = bn * 256 + wave * 64;
    int r0 = bm * 64;

    float4v acc[4][4];
#pragma unroll
    for (int mt = 0; mt < 4; mt++)
#pragma unroll
        for (int nt = 0; nt < 4; nt++) acc[mt][nt] = (float4v)(0.f);

#pragma unroll
    for (int k0 = 0; k0 < NODE_F; k0 += 32) {
        int kk = k0 + quad * 8;
        short8 a0 = *(const short8*)(nf + (r0 + m16) * NODE_F + kk);
        short8 a1 = *(const short8*)(nf + (r0 + 16 + m16) * NODE_F + kk);
        short8 a2 = *(const short8*)(nf + (r0 + 32 + m16) * NODE_F + kk);
        short8 a3 = *(const short8*)(nf + (r0 + 48 + m16) * NODE_F + kk);
#pragma unroll
        for (int nt = 0; nt < 4; nt++) {
            int n = base + nt * 16 + m16;
            short8 b = *(const short8*)(wijT + n * NODE_F + kk);
            acc[0][nt] = __builtin_amdgcn_mfma_f32_16x16x32_bf16(a0, b, acc[0][nt], 0, 0, 0);
            acc[1][nt] = __builtin_amdgcn_mfma_f32_16x16x32_bf16(a1, b, acc[1][nt], 0, 0, 0);
            acc[2][nt] = __builtin_amdgcn_mfma_f32_16x16x32_bf16(a2, b, acc[2][nt], 0, 0, 0);
            acc[3][nt] = __builtin_amdgcn_mfma_f32_16x16x32_bf16(a3, b, acc[3][nt], 0, 0, 0);
        }
    }
#pragma unroll
    for (int nt = 0; nt < 4; nt++) {
        int colg = base + nt * 16 + m16;
#pragma unroll
        for (int mt = 0; mt < 4; mt++)
#pragma unroll
            for (int t = 0; t < 4; t++) {
                int rr = r0 + mt * 16 + quad * 4 + t;
                UV[(size_t)rr * 1024 + colg] = f2bf(acc[mt][nt][t]);
            }
    }
}

// ---------------- fused edge, persistent-B: grid 512 x 512thr; block = 5 tiles of one batch.
// B (32 cols x 512 k per wave) lives in 128 VGPRs for the whole block.
// h1 double-buffered; next-tile UV gathers overlap current GEMM; all loads
// consumed before barriers (no vmcnt-drain loss).
__global__ __launch_bounds__(512, 2) void k_edge7(
    const float* __restrict__ Zc, const ushort* __restrict__ UV,
    const ushort* __restrict__ ew2T, const float* __restrict__ ew3,
    const float* __restrict__ eb2, const float* __restrict__ eb3,
    const int* __restrict__ ptab, float* __restrict__ out_edges)
{
    __shared__ __align__(16) ushort h1[2][MTILE][HIDDEN + 8]; // 133,120 B
    __shared__ float part[MTILE][8];                          // 2,048 B
    __shared__ int uo5[TPB][MTILE], vo5[TPB][MTILE];          // 2,560 B

    int tid  = threadIdx.x;
    int blk  = blockIdx.x;
    int b    = blk >> 2;             // batch
    int ti0  = (blk & 3) * TPB;      // first tile-in-batch

    if (tid < MTILE) {
#pragma unroll
        for (int t = 0; t < TPB; t++) {
            int p = (ti0 + t) * MTILE + tid;
            if (p >= NPAIRS) p = NPAIRS - 1;
            int ij = ptab[p];
            uo5[t][tid] = (b * MAX_NODES + (ij >> 8)) * 1024;
            vo5[t][tid] = (b * MAX_NODES + (ij & 255)) * 1024 + 512;
        }
    }

    int wave = tid >> 6, lane = tid & 63;
    int m16 = lane & 15, quad = lane >> 4;
    int c8 = lane * 8;
    int kk0 = quad * 8;

    // Zc slice (reused all tiles)
    float4v zA = *(const float4v*)(Zc + b * HIDDEN + c8);
    float4v zB = *(const float4v*)(Zc + b * HIDDEN + c8 + 4);

    // persistent B: wave covers cols [wave*32, wave*32+32)
    const ushort* bb0 = ew2T + (wave * 32 + m16) * HIDDEN;
    const ushort* bb1 = ew2T + (wave * 32 + 16 + m16) * HIDDEN;
    short8 Breg[16][2];
#pragma unroll
    for (int kc = 0; kc < 16; kc++) {
        Breg[kc][0] = *(const short8*)(bb0 + kc * 32 + kk0);
        Breg[kc][1] = *(const short8*)(bb1 + kc * 32 + kk0);
    }
    float eb2v[2], ew3v[2];
    eb2v[0] = eb2[wave * 32 + m16];      eb2v[1] = eb2[wave * 32 + 16 + m16];
    ew3v[0] = ew3[wave * 32 + m16];      ew3v[1] = ew3[wave * 32 + 16 + m16];

    __syncthreads();   // uo5/vo5 ready

    // ---- assemble tile 0 into buf 0 (wave rows [wave*8, +8), lane cols [8l,+8))
#pragma unroll
    for (int rr = 0; rr < 8; rr++) {
        int r = wave * 8 + rr;
        short8 u8 = *(const short8*)(UV + uo5[0][r] + c8);
        short8 v8 = *(const short8*)(UV + vo5[0][r] + c8);
        short8 hh;
#pragma unroll
        for (int e = 0; e < 8; e++) {
            float zz = (e < 4) ? zA[e] : zB[e - 4];
            hh[e] = (short)f2bf(fmaxf(zz + bf2f((ushort)u8[e]) + bf2f((ushort)v8[e]), 0.f));
        }
        *(short8*)&h1[0][r][c8] = hh;
    }
    __syncthreads();

    for (int t = 0; t < TPB; t++) {
        int cur = t & 1, nxt = cur ^ 1;
        bool hasNext = (t + 1 < TPB);

        float4v acc2[4][2];
#pragma unroll
        for (int mt = 0; mt < 4; mt++)
#pragma unroll
            for (int nt = 0; nt < 2; nt++) acc2[mt][nt] = (float4v)(0.f);

        // prefetch rows 0-3 of next tile
        short8 uu[4], vv[4];
        if (hasNext) {
#pragma unroll
            for (int rr = 0; rr < 4; rr++) {
                int r = wave * 8 + rr;
                uu[rr] = *(const short8*)(UV + uo5[t + 1][r] + c8);
                vv[rr] = *(const short8*)(UV + vo5[t + 1][r] + c8);
            }
        }
        // GEMM k-iters 0..7 (B from regs, A from LDS)
#pragma unroll
        for (int it = 0; it < 8; ++it) {
            int kk = it * 32 + kk0;
            short8 a0 = *(const short8*)&h1[cur][m16][kk];
            short8 a1 = *(const short8*)&h1[cur][16 + m16][kk];
            short8 a2 = *(const short8*)&h1[cur][32 + m16][kk];
            short8 a3 = *(const short8*)&h1[cur][48 + m16][kk];
            acc2[0][0] = __builtin_amdgcn_mfma_f32_16x16x32_bf16(a0, Breg[it][0], acc2[0][0], 0, 0, 0);
            acc2[1][0] = __builtin_amdgcn_mfma_f32_16x16x32_bf16(a1, Breg[it][0], acc2[1][0], 0, 0, 0);
            acc2[2][0] = __builtin_amdgcn_mfma_f32_16x16x32_bf16(a2, Breg[it][0], acc2[2][0], 0, 0, 0);
            acc2[3][0] = __builtin_amdgcn_mfma_f32_16x16x32_bf16(a3, Breg[it][0], acc2[3][0], 0, 0, 0);
            acc2[0][1] = __builtin_amdgcn_mfma_f32_16x16x32_bf16(a0, Breg[it][1], acc2[0][1], 0, 0, 0);
            acc2[1][1] = __builtin_amdgcn_mfma_f32_16x16x32_bf16(a1, Breg[it][1], acc2[1][1], 0, 0, 0);
            acc2[2][1] = __builtin_amdgcn_mfma_f32_16x16x32_bf16(a2, Breg[it][1], acc2[2][1], 0, 0, 0);
            acc2[3][1] = __builtin_amdgcn_mfma_f32_16x16x32_bf16(a3, Breg[it][1], acc2[3][1], 0, 0, 0);
        }
        // consume prefetch: write rows 0-3 of next tile
        if (hasNext) {
#pragma unroll
            for (int rr = 0; rr < 4; rr++) {
                int r = wave * 8 + rr;
                short8 hh;
#pragma unroll
                for (int e = 0; e < 8; e++) {
                    float zz = (e < 4) ? zA[e] : zB[e - 4];
                    hh[e] = (short)f2bf(fmaxf(zz + bf2f((ushort)uu[rr][e]) + bf2f((ushort)vv[rr][e]), 0.f));
                }
                *(short8*)&h1[nxt][r][c8] = hh;
            }
            // prefetch rows 4-7
#pragma unroll
            for (int rr = 0; rr < 4; rr++) {
                int r = wave * 8 + 4 + rr;
                uu[rr] = *(const short8*)(UV + uo5[t + 1][r] + c8);
                vv[rr] = *(const short8*)(UV + vo5[t + 1][r] + c8);
            }
        }
        // GEMM k-iters 8..15
#pragma unroll
        for (int it = 8; it < 16; ++it) {
            int kk = it * 32 + kk0;
            short8 a0 = *(const short8*)&h1[cur][m16][kk];
            short8 a1 = *(const short8*)&h1[cur][16 + m16][kk];
            short8 a2 = *(const short8*)&h1[cur][32 + m16][kk];
            short8 a3 = *(const short8*)&h1[cur][48 + m16][kk];
            acc2[0][0] = __builtin_amdgcn_mfma_f32_16x16x32_bf16(a0, Breg[it][0], acc2[0][0], 0, 0, 0);
            acc2[1][0] = __builtin_amdgcn_mfma_f32_16x16x32_bf16(a1, Breg[it][0], acc2[1][0], 0, 0, 0);
            acc2[2][0] = __builtin_amdgcn_mfma_f32_16x16x32_bf16(a2, Breg[it][0], acc2[2][0], 0, 0, 0);
            acc2[3][0] = __builtin_amdgcn_mfma_f32_16x16x32_bf16(a3, Breg[it][0], acc2[3][0], 0, 0, 0);
            acc2[0][1] = __builtin_amdgcn_mfma_f32_16x16x32_bf16(a0, Breg[it][1], acc2[0][1], 0, 0, 0);
            acc2[1][1] = __builtin_amdgcn_mfma_f32_16x16x32_bf16(a1, Breg[it][1], acc2[1][1], 0, 0, 0);
            acc2[2][1] = __builtin_amdgcn_mfma_f32_16x16x32_bf16(a2, Breg[it][1], acc2[2][1], 0, 0, 0);
            acc2[3][1] = __builtin_amdgcn_mfma_f32_16x16x32_bf16(a3, Breg[it][1], acc2[3][1], 0, 0, 0);
        }
        // consume prefetch: write rows 4-7 of next tile
        if (hasNext) {
#pragma unroll
            for (int rr = 0; rr < 4; rr++) {
                int r = wave * 8 + 4 + rr;
                short8 hh;
#pragma unroll
                for (int e = 0; e < 8; e++) {
                    float zz = (e < 4) ? zA[e] : zB[e - 4];
                    hh[e] = (short)f2bf(fmaxf(zz + bf2f((ushort)uu[rr][e]) + bf2f((ushort)vv[rr][e]), 0.f));
                }
                *(short8*)&h1[nxt][r][c8] = hh;
            }
        }

        // epilogue: fused relu + partial dot (32 cols) via shfl-reduce
#pragma unroll
        for (int mt = 0; mt < 4; mt++)
#pragma unroll
            for (int tt = 0; tt < 4; tt++) {
                float s = 0.f;
#pragma unroll
                for (int nt = 0; nt < 2; nt++)
                    s += fmaxf(acc2[mt][nt][tt] + eb2v[nt], 0.f) * ew3v[nt];
                s += __shfl_xor(s, 1);
                s += __shfl_xor(s, 2);
                s += __shfl_xor(s, 4);
                s += __shfl_xor(s, 8);
                if (m16 == 0) part[mt * 16 + quad * 4 + tt][wave] = s;
            }
        __syncthreads();

        if (tid < MTILE) {
            int p = (ti0 + t) * MTILE + tid;
            if (p < NPAIRS) {
                float v = eb3[0];
#pragma unroll
                for (int w = 0; w < 8; w++) v += part[tid][w];
                out_edges[b * NPAIRS + p] = sigmoidf(v);
            }
        }
        __syncthreads();   // protect part[] before next tile's epilogue
    }
}

extern "C" void kernel_launch(void* const* d_in, const int* in_sizes, int n_in,
                              void* d_out, int out_size, void* d_ws, size_t ws_size,
                              hipStream_t stream) {
    const float* z   = (const float*)d_in[0];
    const float* nw1 = (const float*)d_in[1];
    const float* nb1 = (const float*)d_in[2];
    const float* nw2 = (const float*)d_in[3];
    const float* nb2 = (const float*)d_in[4];
    const float* nw3 = (const float*)d_in[5];
    const float* nb3 = (const float*)d_in[6];
    const float* ew1 = (const float*)d_in[7];
    const float* eb1 = (const float*)d_in[8];
    const float* ew2 = (const float*)d_in[9];
    const float* eb2 = (const float*)d_in[10];
    const float* ew3 = (const float*)d_in[11];
    const float* eb3 = (const float*)d_in[12];

    char* ws = (char*)d_ws;
    int*    ptab = (int*)(ws);                       // 1225*4
    ushort* h2b  = (ushort*)(ws + 262144);           // 131072
    ushort* nf   = (ushort*)(ws + 393216);           // 1638400
    ushort* ew2T = (ushort*)(ws + 2031616);          // 262144
    ushort* wijT = (ushort*)(ws + 2293760);          // 262144
    ushort* nw3T = (ushort*)(ws + 2555904);          // 6553600
    float*  Zc   = (float*)(ws + 9109504);           // 262144
    ushort* UV   = (ushort*)(ws + 9371648);          // 13107200

    float* out_nodes = (float*)d_out;                // 128*6400
    float* out_edges = out_nodes + BATCH * NODE_OUT; // 128*1225

    k_prep_all<<<PREPK_NB, 256, 0, stream>>>(nw3, nw3T, ew1, ew2, ew2T, wijT,
                                             z, eb1, Zc, nw1, nb1, nw2, nb2,
                                             h2b, ptab);
    k_node_out_mfma<<<400, 256, 0, stream>>>(h2b, nw3T, nb3, out_nodes, nf);
    k_uv<<<400, 256, 0, stream>>>(nf, wijT, UV);
    k_edge7<<<EDGE_BLOCKS, 512, 0, stream>>>(Zc, UV, ew2T, ew3,
                                             eb2, eb3, ptab, out_edges);
}

// Round 11
// 225.785 us; speedup vs baseline: 3.0302x; 1.0294x over previous
//
#include <hip/hip_runtime.h>
#include <hip/hip_bf16.h>
#include <math.h>

#define LATENT 256
#define HIDDEN 512
#define NODE_F 128
#define MAX_NODES 50
#define NPAIRS 1225        // 50*49/2
#define BATCH 128
#define NODE_OUT 6400      // MAX_NODES*NODE_F
#define MTILE 64           // edge rows per tile
#define TPB 10             // tiles per block (20 tiles/batch = 2 blocks/batch)
#define EDGE_BLOCKS 256    // 128 batches * 2  (exactly 1 block/CU)

typedef __attribute__((ext_vector_type(8))) short short8;
typedef __attribute__((ext_vector_type(4))) float float4v;

union S8U { short8 s; unsigned int u[4]; };

__device__ __forceinline__ float bf2f(ushort u) {
    union { unsigned int i; float f; } v; v.i = ((unsigned int)u) << 16; return v.f;
}
__device__ __forceinline__ ushort f2bf(float f) {
    union { unsigned int i; float f; } v; v.f = f;
    unsigned int r = v.i + 0x7fffu + ((v.i >> 16) & 1u);   // RNE
    return (ushort)(r >> 16);
}
__device__ __forceinline__ unsigned int pk_bf16(float f0, float f1) {
    __hip_bfloat162 p = __float22bfloat162_rn(float2{f0, f1});   // v_cvt_pk_bf16_f32 (RNE)
    unsigned int w; __builtin_memcpy(&w, &p, 4); return w;
}
__device__ __forceinline__ float sigmoidf(float x) {
    return 1.0f / (1.0f + __expf(-x));
}

// ================= fused prep kernel: 5 independent jobs, one launch =================
#define TR3_B0   0
#define PREP_B0  800
#define ZC_B0    1824
#define ND_B0    2080
#define PT_B0    2336
#define PREPK_NB 2341

__global__ __launch_bounds__(256) void k_prep_all(
    const float* __restrict__ nw3, ushort* __restrict__ nw3T,
    const float* __restrict__ ew1, const float* __restrict__ ew2,
    ushort* __restrict__ ew2T, ushort* __restrict__ wijT,
    const float* __restrict__ z, const float* __restrict__ eb1,
    float* __restrict__ Zc,
    const float* __restrict__ nw1, const float* __restrict__ nb1,
    const float* __restrict__ nw2, const float* __restrict__ nb2,
    ushort* __restrict__ h2b, int* __restrict__ ptab)
{
    __shared__ float smem[64 * 65];
    int b = blockIdx.x;
    int tid = threadIdx.x;

    if (b < PREP_B0) {
        int bb = b - TR3_B0;
        int k0 = (bb & 7) * 64;
        int n0 = (bb >> 3) * 64;
        int tx = tid & 63, ty = tid >> 6;   // 64 x 4
#pragma unroll
        for (int r = 0; r < 16; r++) {
            int row = r * 4 + ty;
            smem[row * 65 + tx] = nw3[(k0 + row) * NODE_OUT + n0 + tx];
        }
        __syncthreads();
#pragma unroll
        for (int c = 0; c < 16; c++) {
            int n = c * 4 + ty;
            nw3T[(size_t)(n0 + n) * HIDDEN + k0 + tx] = f2bf(smem[tx * 65 + n]);
        }
    } else if (b < ZC_B0) {
        int t = (b - PREP_B0) * 256 + tid;
        if (t < 256 * 512) {
            int n = t >> 9, k = t & 511;
            ew2T[t] = f2bf(ew2[k * 256 + n]);
        } else {
            int u = t - 256 * 512;          // < 1024*128
            int n = u >> 7, k = u & 127;
            float s = (n < 512) ? ew1[(256 + k) * 512 + n] : ew1[(384 + k) * 512 + (n - 512)];
            wijT[u] = f2bf(s);
        }
    } else if (b < ND_B0) {
        // ---- Zc = z @ W_z + eb1
        int b2 = b - ZC_B0;
        int r = b2 >> 1, o = (b2 & 1) * 256 + tid;
        float* zs = smem;
        zs[tid] = z[r * LATENT + tid];
        __syncthreads();
        float acc = 0.f;
#pragma unroll 8
        for (int k = 0; k < LATENT; k++) acc += zs[k] * ew1[k * HIDDEN + o];
        Zc[r * HIDDEN + o] = acc + eb1[o];
    } else if (b < PT_B0) {
        // ---- fused node MLP L1+L2
        int b2 = b - ND_B0;
        int r = b2 >> 1, half = b2 & 1;
        float* zs = smem;            // 256 floats
        float* hs = smem + 256;      // 512 floats
        zs[tid] = z[r * LATENT + tid];
        __syncthreads();
        float a0 = 0.f, a1 = 0.f;
#pragma unroll 8
        for (int k = 0; k < LATENT; k++) {
            float zk = zs[k];
            a0 += zk * nw1[k * HIDDEN + tid];
            a1 += zk * nw1[k * HIDDEN + tid + 256];
        }
        hs[tid]       = fmaxf(a0 + nb1[tid], 0.f);
        hs[tid + 256] = fmaxf(a1 + nb1[tid + 256], 0.f);
        __syncthreads();
        int o = half * 256 + tid;
        float acc = 0.f;
#pragma unroll 8
        for (int k = 0; k < HIDDEN; k++) acc += hs[k] * nw2[k * HIDDEN + o];
        acc += nb2[o];
        h2b[r * HIDDEN + o] = f2bf(fmaxf(acc, 0.f));
    } else {
        int p = (b - PT_B0) * 256 + tid;
        if (p < NPAIRS) {
            int i = 0, off = 0;
            while (p - off >= MAX_NODES - 1 - i) { off += MAX_NODES - 1 - i; ++i; }
            int j = i + 1 + (p - off);
            ptab[p] = (i << 8) | j;
        }
    }
}

// ---------------- node layer 3 via MFMA: grid 200 = 100 n-tiles(64) x 2 m-halves(64)
// B (nw3T) read 2x total (was 4x); mt=4 rows per wave-pass.
__global__ __launch_bounds__(256, 4) void k_node_out_mfma(
    const ushort* __restrict__ h2b, const ushort* __restrict__ nw3T,
    const float* __restrict__ nb3, float* __restrict__ node_probs,
    ushort* __restrict__ node_feats)
{
    int tid = threadIdx.x;
    int wave = tid >> 6, lane = tid & 63;
    int m16 = lane & 15, quad = lane >> 4;
    int n0 = (blockIdx.x >> 1) * 64;
    int m0 = (blockIdx.x & 1) * 64;
    int col = n0 + wave * 16 + m16;

    float4v acc[4];
#pragma unroll
    for (int mt = 0; mt < 4; mt++) acc[mt] = (float4v)(0.f);

    const ushort* bb = nw3T + (size_t)col * HIDDEN;
#pragma unroll
    for (int it = 0; it < 16; ++it) {
        int kk = it * 32 + quad * 8;
        short8 b = *(const short8*)(bb + kk);
#pragma unroll
        for (int mt = 0; mt < 4; mt++) {
            short8 a = *(const short8*)(h2b + (m0 + mt * 16 + m16) * HIDDEN + kk);
            acc[mt] = __builtin_amdgcn_mfma_f32_16x16x32_bf16(a, b, acc[mt], 0, 0, 0);
        }
    }
    float bias = nb3[col];
#pragma unroll
    for (int mt = 0; mt < 4; mt++)
#pragma unroll
        for (int t = 0; t < 4; t++) {
            int row = m0 + mt * 16 + quad * 4 + t;
            float v = acc[mt][t] + bias;
            node_probs[(size_t)row * NODE_OUT + col] = sigmoidf(v);
            node_feats[(size_t)row * NODE_OUT + col] = f2bf(v);
        }
}

// ---------------- UV = node_feats @ [W_i|W_j]   (6400 x 1024, bf16 out)
__global__ __launch_bounds__(256, 4) void k_uv(
    const ushort* __restrict__ nf, const ushort* __restrict__ wijT,
    ushort* __restrict__ UV)
{
    int tid = threadIdx.x;
    int wave = tid >> 6, lane = tid & 63;
    int m16 = lane & 15, quad = lane >> 4;
    int bm = blockIdx.x >> 2, bn = blockIdx.x & 3;
    int base = bn * 256 + wave * 64;
    int r0 = bm * 64;

    float4v acc[4][4];
#pragma unroll
    for (int mt = 0; mt < 4; mt++)
#pragma unroll
        for (int nt = 0; nt < 4; nt++) acc[mt][nt] = (float4v)(0.f);

#pragma unroll
    for (int k0 = 0; k0 < NODE_F; k0 += 32) {
        int kk = k0 + quad * 8;
        short8 a0 = *(const short8*)(nf + (r0 + m16) * NODE_F + kk);
        short8 a1 = *(const short8*)(nf + (r0 + 16 + m16) * NODE_F + kk);
        short8 a2 = *(const short8*)(nf + (r0 + 32 + m16) * NODE_F + kk);
        short8 a3 = *(const short8*)(nf + (r0 + 48 + m16) * NODE_F + kk);
#pragma unroll
        for (int nt = 0; nt < 4; nt++) {
            int n = base + nt * 16 + m16;
            short8 b = *(const short8*)(wijT + n * NODE_F + kk);
            acc[0][nt] = __builtin_amdgcn_mfma_f32_16x16x32_bf16(a0, b, acc[0][nt], 0, 0, 0);
            acc[1][nt] = __builtin_amdgcn_mfma_f32_16x16x32_bf16(a1, b, acc[1][nt], 0, 0, 0);
            acc[2][nt] = __builtin_amdgcn_mfma_f32_16x16x32_bf16(a2, b, acc[2][nt], 0, 0, 0);
            acc[3][nt] = __builtin_amdgcn_mfma_f32_16x16x32_bf16(a3, b, acc[3][nt], 0, 0, 0);
        }
    }
#pragma unroll
    for (int nt = 0; nt < 4; nt++) {
        int colg = base + nt * 16 + m16;
#pragma unroll
        for (int mt = 0; mt < 4; mt++)
#pragma unroll
            for (int t = 0; t < 4; t++) {
                int rr = r0 + mt * 16 + quad * 4 + t;
                UV[(size_t)rr * 1024 + colg] = f2bf(acc[mt][nt][t]);
            }
    }
}

// ---------------- fused edge, persistent-B, TPB=10, grid 256 (1 block/CU, 1 round)
__global__ __launch_bounds__(512, 2) void k_edge8(
    const float* __restrict__ Zc, const ushort* __restrict__ UV,
    const ushort* __restrict__ ew2T, const float* __restrict__ ew3,
    const float* __restrict__ eb2, const float* __restrict__ eb3,
    const int* __restrict__ ptab, float* __restrict__ out_edges)
{
    __shared__ __align__(16) ushort h1[2][MTILE][HIDDEN + 8]; // 133,120 B
    __shared__ float part[MTILE][8];                          // 2,048 B
    __shared__ int uo5[TPB][MTILE], vo5[TPB][MTILE];          // 5,120 B

    int tid  = threadIdx.x;
    int blk  = blockIdx.x;
    int b    = blk >> 1;             // batch
    int ti0  = (blk & 1) * TPB;      // first tile-in-batch

    if (tid < MTILE) {
#pragma unroll
        for (int t = 0; t < TPB; t++) {
            int p = (ti0 + t) * MTILE + tid;
            if (p >= NPAIRS) p = NPAIRS - 1;
            int ij = ptab[p];
            uo5[t][tid] = (b * MAX_NODES + (ij >> 8)) * 1024;
            vo5[t][tid] = (b * MAX_NODES + (ij & 255)) * 1024 + 512;
        }
    }

    int wave = tid >> 6, lane = tid & 63;
    int m16 = lane & 15, quad = lane >> 4;
    int c8 = lane * 8;
    int kk0 = quad * 8;

    float4v zA = *(const float4v*)(Zc + b * HIDDEN + c8);
    float4v zB = *(const float4v*)(Zc + b * HIDDEN + c8 + 4);

    // persistent B: wave covers cols [wave*32, wave*32+32)
    const ushort* bb0 = ew2T + (wave * 32 + m16) * HIDDEN;
    const ushort* bb1 = ew2T + (wave * 32 + 16 + m16) * HIDDEN;
    short8 Breg[16][2];
#pragma unroll
    for (int kc = 0; kc < 16; kc++) {
        Breg[kc][0] = *(const short8*)(bb0 + kc * 32 + kk0);
        Breg[kc][1] = *(const short8*)(bb1 + kc * 32 + kk0);
    }
    float eb2v[2], ew3v[2];
    eb2v[0] = eb2[wave * 32 + m16];      eb2v[1] = eb2[wave * 32 + 16 + m16];
    ew3v[0] = ew3[wave * 32 + m16];      ew3v[1] = ew3[wave * 32 + 16 + m16];

    __syncthreads();   // uo5/vo5 ready

    // ---- assemble tile 0 into buf 0
#pragma unroll
    for (int rr = 0; rr < 8; rr++) {
        int r = wave * 8 + rr;
        short8 u8 = *(const short8*)(UV + uo5[0][r] + c8);
        short8 v8 = *(const short8*)(UV + vo5[0][r] + c8);
        S8U hh;
#pragma unroll
        for (int e2 = 0; e2 < 4; e2++) {
            float z0 = (e2 < 2) ? zA[e2 * 2] : zB[e2 * 2 - 4];
            float z1 = (e2 < 2) ? zA[e2 * 2 + 1] : zB[e2 * 2 - 3];
            float f0 = fmaxf(z0 + bf2f((ushort)u8[e2 * 2]) + bf2f((ushort)v8[e2 * 2]), 0.f);
            float f1 = fmaxf(z1 + bf2f((ushort)u8[e2 * 2 + 1]) + bf2f((ushort)v8[e2 * 2 + 1]), 0.f);
            hh.u[e2] = pk_bf16(f0, f1);
        }
        *(short8*)&h1[0][r][c8] = hh.s;
    }
    __syncthreads();

    for (int t = 0; t < TPB; t++) {
        int cur = t & 1, nxt = cur ^ 1;
        bool hasNext = (t + 1 < TPB);

        float4v acc2[4][2];
#pragma unroll
        for (int mt = 0; mt < 4; mt++)
#pragma unroll
            for (int nt = 0; nt < 2; nt++) acc2[mt][nt] = (float4v)(0.f);

        short8 uu[4], vv[4];
        if (hasNext) {
#pragma unroll
            for (int rr = 0; rr < 4; rr++) {
                int r = wave * 8 + rr;
                uu[rr] = *(const short8*)(UV + uo5[t + 1][r] + c8);
                vv[rr] = *(const short8*)(UV + vo5[t + 1][r] + c8);
            }
        }
#pragma unroll
        for (int it = 0; it < 8; ++it) {
            int kk = it * 32 + kk0;
            short8 a0 = *(const short8*)&h1[cur][m16][kk];
            short8 a1 = *(const short8*)&h1[cur][16 + m16][kk];
            short8 a2 = *(const short8*)&h1[cur][32 + m16][kk];
            short8 a3 = *(const short8*)&h1[cur][48 + m16][kk];
            acc2[0][0] = __builtin_amdgcn_mfma_f32_16x16x32_bf16(a0, Breg[it][0], acc2[0][0], 0, 0, 0);
            acc2[1][0] = __builtin_amdgcn_mfma_f32_16x16x32_bf16(a1, Breg[it][0], acc2[1][0], 0, 0, 0);
            acc2[2][0] = __builtin_amdgcn_mfma_f32_16x16x32_bf16(a2, Breg[it][0], acc2[2][0], 0, 0, 0);
            acc2[3][0] = __builtin_amdgcn_mfma_f32_16x16x32_bf16(a3, Breg[it][0], acc2[3][0], 0, 0, 0);
            acc2[0][1] = __builtin_amdgcn_mfma_f32_16x16x32_bf16(a0, Breg[it][1], acc2[0][1], 0, 0, 0);
            acc2[1][1] = __builtin_amdgcn_mfma_f32_16x16x32_bf16(a1, Breg[it][1], acc2[1][1], 0, 0, 0);
            acc2[2][1] = __builtin_amdgcn_mfma_f32_16x16x32_bf16(a2, Breg[it][1], acc2[2][1], 0, 0, 0);
            acc2[3][1] = __builtin_amdgcn_mfma_f32_16x16x32_bf16(a3, Breg[it][1], acc2[3][1], 0, 0, 0);
        }
        if (hasNext) {
#pragma unroll
            for (int rr = 0; rr < 4; rr++) {
                int r = wave * 8 + rr;
                S8U hh;
#pragma unroll
                for (int e2 = 0; e2 < 4; e2++) {
                    float z0 = (e2 < 2) ? zA[e2 * 2] : zB[e2 * 2 - 4];
                    float z1 = (e2 < 2) ? zA[e2 * 2 + 1] : zB[e2 * 2 - 3];
                    float f0 = fmaxf(z0 + bf2f((ushort)uu[rr][e2 * 2]) + bf2f((ushort)vv[rr][e2 * 2]), 0.f);
                    float f1 = fmaxf(z1 + bf2f((ushort)uu[rr][e2 * 2 + 1]) + bf2f((ushort)vv[rr][e2 * 2 + 1]), 0.f);
                    hh.u[e2] = pk_bf16(f0, f1);
                }
                *(short8*)&h1[nxt][r][c8] = hh.s;
            }
#pragma unroll
            for (int rr = 0; rr < 4; rr++) {
                int r = wave * 8 + 4 + rr;
                uu[rr] = *(const short8*)(UV + uo5[t + 1][r] + c8);
                vv[rr] = *(const short8*)(UV + vo5[t + 1][r] + c8);
            }
        }
#pragma unroll
        for (int it = 8; it < 16; ++it) {
            int kk = it * 32 + kk0;
            short8 a0 = *(const short8*)&h1[cur][m16][kk];
            short8 a1 = *(const short8*)&h1[cur][16 + m16][kk];
            short8 a2 = *(const short8*)&h1[cur][32 + m16][kk];
            short8 a3 = *(const short8*)&h1[cur][48 + m16][kk];
            acc2[0][0] = __builtin_amdgcn_mfma_f32_16x16x32_bf16(a0, Breg[it][0], acc2[0][0], 0, 0, 0);
            acc2[1][0] = __builtin_amdgcn_mfma_f32_16x16x32_bf16(a1, Breg[it][0], acc2[1][0], 0, 0, 0);
            acc2[2][0] = __builtin_amdgcn_mfma_f32_16x16x32_bf16(a2, Breg[it][0], acc2[2][0], 0, 0, 0);
            acc2[3][0] = __builtin_amdgcn_mfma_f32_16x16x32_bf16(a3, Breg[it][0], acc2[3][0], 0, 0, 0);
            acc2[0][1] = __builtin_amdgcn_mfma_f32_16x16x32_bf16(a0, Breg[it][1], acc2[0][1], 0, 0, 0);
            acc2[1][1] = __builtin_amdgcn_mfma_f32_16x16x32_bf16(a1, Breg[it][1], acc2[1][1], 0, 0, 0);
            acc2[2][1] = __builtin_amdgcn_mfma_f32_16x16x32_bf16(a2, Breg[it][1], acc2[2][1], 0, 0, 0);
            acc2[3][1] = __builtin_amdgcn_mfma_f32_16x16x32_bf16(a3, Breg[it][1], acc2[3][1], 0, 0, 0);
        }
        if (hasNext) {
#pragma unroll
            for (int rr = 0; rr < 4; rr++) {
                int r = wave * 8 + 4 + rr;
                S8U hh;
#pragma unroll
                for (int e2 = 0; e2 < 4; e2++) {
                    float z0 = (e2 < 2) ? zA[e2 * 2] : zB[e2 * 2 - 4];
                    float z1 = (e2 < 2) ? zA[e2 * 2 + 1] : zB[e2 * 2 - 3];
                    float f0 = fmaxf(z0 + bf2f((ushort)uu[rr][e2 * 2]) + bf2f((ushort)vv[rr][e2 * 2]), 0.f);
                    float f1 = fmaxf(z1 + bf2f((ushort)uu[rr][e2 * 2 + 1]) + bf2f((ushort)vv[rr][e2 * 2 + 1]), 0.f);
                    hh.u[e2] = pk_bf16(f0, f1);
                }
                *(short8*)&h1[nxt][r][c8] = hh.s;
            }
        }

        // epilogue: fused relu + partial dot (32 cols) via shfl-reduce
#pragma unroll
        for (int mt = 0; mt < 4; mt++)
#pragma unroll
            for (int tt = 0; tt < 4; tt++) {
                float s = 0.f;
#pragma unroll
                for (int nt = 0; nt < 2; nt++)
                    s += fmaxf(acc2[mt][nt][tt] + eb2v[nt], 0.f) * ew3v[nt];
                s += __shfl_xor(s, 1);
                s += __shfl_xor(s, 2);
                s += __shfl_xor(s, 4);
                s += __shfl_xor(s, 8);
                if (m16 == 0) part[mt * 16 + quad * 4 + tt][wave] = s;
            }
        __syncthreads();

        if (tid < MTILE) {
            int p = (ti0 + t) * MTILE + tid;
            if (p < NPAIRS) {
                float v = eb3[0];
#pragma unroll
                for (int w = 0; w < 8; w++) v += part[tid][w];
                out_edges[b * NPAIRS + p] = sigmoidf(v);
            }
        }
        __syncthreads();
    }
}

extern "C" void kernel_launch(void* const* d_in, const int* in_sizes, int n_in,
                              void* d_out, int out_size, void* d_ws, size_t ws_size,
                              hipStream_t stream) {
    const float* z   = (const float*)d_in[0];
    const float* nw1 = (const float*)d_in[1];
    const float* nb1 = (const float*)d_in[2];
    const float* nw2 = (const float*)d_in[3];
    const float* nb2 = (const float*)d_in[4];
    const float* nw3 = (const float*)d_in[5];
    const float* nb3 = (const float*)d_in[6];
    const float* ew1 = (const float*)d_in[7];
    const float* eb1 = (const float*)d_in[8];
    const float* ew2 = (const float*)d_in[9];
    const float* eb2 = (const float*)d_in[10];
    const float* ew3 = (const float*)d_in[11];
    const float* eb3 = (const float*)d_in[12];

    char* ws = (char*)d_ws;
    int*    ptab = (int*)(ws);                       // 1225*4
    ushort* h2b  = (ushort*)(ws + 262144);           // 131072
    ushort* nf   = (ushort*)(ws + 393216);           // 1638400
    ushort* ew2T = (ushort*)(ws + 2031616);          // 262144
    ushort* wijT = (ushort*)(ws + 2293760);          // 262144
    ushort* nw3T = (ushort*)(ws + 2555904);          // 6553600
    float*  Zc   = (float*)(ws + 9109504);           // 262144
    ushort* UV   = (ushort*)(ws + 9371648);          // 13107200

    float* out_nodes = (float*)d_out;                // 128*6400
    float* out_edges = out_nodes + BATCH * NODE_OUT; // 128*1225

    k_prep_all<<<PREPK_NB, 256, 0, stream>>>(nw3, nw3T, ew1, ew2, ew2T, wijT,
                                             z, eb1, Zc, nw1, nb1, nw2, nb2,
                                             h2b, ptab);
    k_node_out_mfma<<<200, 256, 0, stream>>>(h2b, nw3T, nb3, out_nodes, nf);
    k_uv<<<400, 256, 0, stream>>>(nf, wijT, UV);
    k_edge8<<<EDGE_BLOCKS, 512, 0, stream>>>(Zc, UV, ew2T, ew3,
                                             eb2, eb3, ptab, out_edges);
}